// Round 10
// baseline (290.131 us; speedup 1.0000x reference)
//
#include <hip/hip_runtime.h>
#include <hip/hip_bf16.h>
#include <stdint.h>

// Problem constants
#define DIMS  2048
#define HEADS 16
#define HD    128
#define BATCH 2
#define SEQ   2048
#define MROWS (BATCH*SEQ)   // 4096
#define QKVN  (3*DIMS)      // 6144
#define QKP   4096          // pitch of QK-only qkv buffer

using bf16x8 = __attribute__((ext_vector_type(8))) short;
using f32x4  = __attribute__((ext_vector_type(4))) float;
using f32x16 = __attribute__((ext_vector_type(16))) float;
using u16x4  = __attribute__((ext_vector_type(4))) unsigned short;

__device__ __forceinline__ unsigned short f2b(float f){
    __hip_bfloat16 h = __float2bfloat16(f);
    return *reinterpret_cast<unsigned short*>(&h);
}
__device__ __forceinline__ float b2f(unsigned short u){
    __hip_bfloat16 h;
    *reinterpret_cast<unsigned short*>(&h) = u;
    return __bfloat162float(h);
}
__device__ __forceinline__ unsigned int pkbf(float lo, float hi){
    return (unsigned int)f2b(lo) | ((unsigned int)f2b(hi) << 16);
}

// async global->LDS, 16B per lane. LDS dest is wave-uniform base (+lane*16 implicit).
__device__ __forceinline__ void glds16(const void* g, void* l){
    __builtin_amdgcn_global_load_lds(
        (const __attribute__((address_space(1))) unsigned int*)g,
        (__attribute__((address_space(3))) unsigned int*)l, 16, 0, 0);
}

// ---------------- fused prep: x->bf16, 4x w->bf16, cos/sin table ----------------
// grid (4096, 7): y 0..3 -> weight y; y 4..5 -> x halves; y 6 -> cossin (1024 blocks active)

__global__ void k_prep(const float* __restrict__ x,
                       const float* __restrict__ w0, const float* __restrict__ w1,
                       const float* __restrict__ w2, const float* __restrict__ w3,
                       const float* __restrict__ rope,
                       unsigned short* __restrict__ x_bf,
                       unsigned short* __restrict__ d0, unsigned short* __restrict__ d1,
                       unsigned short* __restrict__ d2, unsigned short* __restrict__ d3,
                       float* __restrict__ ct, float* __restrict__ st){
    const int y = blockIdx.y;
    if (y == 6){
        const int i = blockIdx.x*blockDim.x + threadIdx.x;
        if (i >= SEQ*HD) return;
        const float v = rope[i];
        ct[i] = cosf(v);
        st[i] = sinf(v);
        return;
    }
    const float* src;
    unsigned short* dst;
    size_t off = 0;
    if      (y == 0){ src = w0; dst = d0; }
    else if (y == 1){ src = w1; dst = d1; }
    else if (y == 2){ src = w2; dst = d2; }
    else if (y == 3){ src = w3; dst = d3; }
    else            { src = x;  dst = x_bf; off = (size_t)(y - 4) * 1048576; }
    const size_t i = off + blockIdx.x*blockDim.x + threadIdx.x;
    const float4 v = reinterpret_cast<const float4*>(src)[i];
    u16x4 o = { f2b(v.x), f2b(v.y), f2b(v.z), f2b(v.w) };
    *reinterpret_cast<u16x4*>(dst + 4*i) = o;
}

// ---------------- 128x128 GEMM (m97 structure) with fused QKV epilogue ----------------
// MODE 0 (QKV): C = qkv [4096][QKP] holds Q,K only (ldc=QKP). Epilogue by region
//   (region = n0>>11): 0=Q plain bf16; 1=K RoPE via TWO-PASS 64-row LDS stash
//   (keeps LDS at 32768B -> 5 blocks/CU); 2=V written TRANSPOSED to vt.
// MODE 1 (out-proj): f32 C + bias, ldc = N.

template<int MODE>
__global__ __launch_bounds__(256) void k_gemm_bt(
    const unsigned short* __restrict__ A, const unsigned short* __restrict__ B,
    void* __restrict__ C, const float* __restrict__ bias,
    unsigned short* __restrict__ vt, const float* __restrict__ ct, const float* __restrict__ st,
    int M, int N, int K, int ldc)
{
    __shared__ unsigned short sbuf[16384];         // lA [0,8192), lB [8192,16384); K-epi reuses [0,8448)
    unsigned short* lA = sbuf;
    unsigned short* lB = sbuf + 8192;

    const int tid  = threadIdx.x;
    const int lane = tid & 63;
    const int wave = tid >> 6;

    const int nbx = N >> 7;
    const int nwg = gridDim.x;
    const int cpx = nwg >> 3;
    const int bid = blockIdx.x;
    const int wg  = (bid & 7)*cpx + (bid >> 3);    // XCD swizzle (nwg%8==0)
    const int m0 = (wg / nbx) << 7;
    const int n0 = (wg % nbx) << 7;

    const int wr = (wave >> 1) << 6;
    const int wc = (wave & 1) << 6;

    f32x4 acc[4][4] = {};

    const int srow_base = (wave<<3) + (lane>>3);
    const int schunk = lane & 7;

    for (int k0 = 0; k0 < K; k0 += 64){
        #pragma unroll
        for (int i = 0; i < 4; ++i){
            const int row  = (i<<5) + srow_base;
            const int scol = k0 + ((schunk ^ (row & 7)) << 3);
            glds16(A + (size_t)(m0 + row)*K + scol, &lA[((i<<5) + (wave<<3)) << 6]);
            glds16(B + (size_t)(n0 + row)*K + scol, &lB[((i<<5) + (wave<<3)) << 6]);
        }
        __syncthreads();
        #pragma unroll
        for (int ks = 0; ks < 2; ++ks){
            bf16x8 af[4], bfr[4];
            const int colbase = (ks<<5) + ((lane>>4)<<3);
            #pragma unroll
            for (int mi = 0; mi < 4; ++mi){
                const int row = wr + (mi<<4) + (lane & 15);
                af[mi] = *reinterpret_cast<const bf16x8*>(&lA[(row<<6) + (colbase ^ ((row&7)<<3))]);
            }
            #pragma unroll
            for (int ni = 0; ni < 4; ++ni){
                const int row = wc + (ni<<4) + (lane & 15);
                bfr[ni] = *reinterpret_cast<const bf16x8*>(&lB[(row<<6) + (colbase ^ ((row&7)<<3))]);
            }
            #pragma unroll
            for (int mi = 0; mi < 4; ++mi)
                #pragma unroll
                for (int ni = 0; ni < 4; ++ni)
                    acc[mi][ni] = __builtin_amdgcn_mfma_f32_16x16x32_bf16(af[mi], bfr[ni], acc[mi][ni], 0, 0, 0);
        }
        __syncthreads();
    }

    // ---- epilogue: D layout col=lane&15, row=(lane>>4)*4+r ----
    const int r0 = (lane >> 4) << 2;
    const int cn = lane & 15;

    if (MODE == 1){
        #pragma unroll
        for (int mi = 0; mi < 4; ++mi)
            #pragma unroll
            for (int r = 0; r < 4; ++r){
                const int gm = m0 + wr + (mi<<4) + r0 + r;
                #pragma unroll
                for (int ni = 0; ni < 4; ++ni){
                    const int gn = n0 + wc + (ni<<4) + cn;
                    reinterpret_cast<float*>(C)[(size_t)gm*ldc + gn] = acc[mi][ni][r] + bias[gn];
                }
            }
        return;
    }

    const int region = n0 >> 11;   // 0=Q, 1=K, 2=V
    if (region == 2){
        // ---- V: write transposed into vt[(b*16+h)*128 + d][l] ----
        const int b   = m0 >> 11;
        const int l0b = m0 & (SEQ-1);
        const int hh  = (n0 - 2*DIMS) >> 7;
        #pragma unroll
        for (int mi = 0; mi < 4; ++mi){
            const int l0 = l0b + wr + (mi<<4) + r0;
            #pragma unroll
            for (int ni = 0; ni < 4; ++ni){
                const int d = wc + (ni<<4) + cn;
                u16x4 w = { f2b(acc[mi][ni][0]), f2b(acc[mi][ni][1]),
                            f2b(acc[mi][ni][2]), f2b(acc[mi][ni][3]) };
                *reinterpret_cast<u16x4*>(
                    &vt[(size_t)(((b<<4) + hh)*HD + d)*SEQ + l0]) = w;
            }
        }
        return;
    }
    if (region == 0){
        // ---- Q: plain bf16, pitch ldc ----
        #pragma unroll
        for (int mi = 0; mi < 4; ++mi)
            #pragma unroll
            for (int r = 0; r < 4; ++r){
                const int gm = m0 + wr + (mi<<4) + r0 + r;
                #pragma unroll
                for (int ni = 0; ni < 4; ++ni){
                    const int gn = n0 + wc + (ni<<4) + cn;
                    reinterpret_cast<unsigned short*>(C)[(size_t)gm*ldc + gn] = f2b(acc[mi][ni][r]);
                }
            }
        return;
    }
    // ---- K: two-pass 64-row LDS stash + RoPE (pairs d, d+64), LDS stays 32KB ----
    // main loop's trailing __syncthreads guarantees lA/lB reads are done.
    unsigned short* Cq = (unsigned short*)C;
    #pragma unroll
    for (int half = 0; half < 2; ++half){
        if ((wave >> 1) == half){
            #pragma unroll
            for (int mi = 0; mi < 4; ++mi)
                #pragma unroll
                for (int r = 0; r < 4; ++r){
                    const int lr = (mi<<4) + r0 + r;            // 0..63 local row
                    #pragma unroll
                    for (int ni = 0; ni < 4; ++ni)
                        sbuf[lr*132 + wc + (ni<<4) + cn] = f2b(acc[mi][ni][r]);
                }
        }
        __syncthreads();
        #pragma unroll
        for (int it = 0; it < 16; ++it){
            const int e  = (it<<8) + tid;
            const int lr = e >> 6;            // 0..63 (wave-uniform)
            const int d  = e & 63;            // = lane
            const int gm = m0 + (half<<6) + lr;
            const int l  = gm & (SEQ-1);
            const float x1 = b2f(sbuf[lr*132 + d]);
            const float x2 = b2f(sbuf[lr*132 + d + 64]);
            const float c0 = ct[l*HD + d],      s0 = st[l*HD + d];
            const float c1 = ct[l*HD + d + 64], s1 = st[l*HD + d + 64];
            unsigned short* rp = Cq + (size_t)gm*ldc + n0;
            rp[d]      = f2b(x1*c0 - x2*s0);
            rp[d + 64] = f2b(x2*c1 + x1*s1);
        }
        __syncthreads();
    }
}

// ---------------- flash attention, swapped-operand 32x32, 4-wave blocks ----------------
// grid (SEQ/128=16, bh=32), block 256 (4 waves x 32 q-rows). KV tile 64, dbuf.
// Q-rope applied in-register at Q-load. QK pitch = QKP (qkv holds Q,K only).
// LDS union 64KB; 2 blocks/CU, 512 blocks = 1 full round.

union U8 { unsigned int w[4]; bf16x8 v; };

__global__ __launch_bounds__(256, 2) void k_attn(
    const unsigned short* __restrict__ qkv, const unsigned short* __restrict__ vt,
    const float* __restrict__ ct, const float* __restrict__ st,
    unsigned short* __restrict__ aout)
{
    __shared__ unsigned short smem[32768];   // 64 KB

    const int tid  = threadIdx.x;
    const int lane = tid & 63;
    const int wave = tid >> 6;               // 0..3
    const int lq   = lane & 31;
    const int hi   = lane >> 5;
    const int bh = blockIdx.y;
    const int b = bh >> 4, h = bh & 15;
    const int q0w = (blockIdx.x << 7) + (wave << 5);

    const unsigned short* Kb = qkv + (size_t)b*SEQ*QKP + DIMS + h*HD;
    const unsigned short* Vb = vt + (size_t)bh*HD*SEQ;

    // Q fragments (B-operand: col=q=lane&31, k=hi*8+j) with in-register RoPE,
    // pre-scaled by log2e/sqrt(HD). d(ks,j) = ks*16 + hi*8 + j; pair = qf[ks+4][j].
    bf16x8 qf[8];
    {
        const float qscale = 0.08838834764831845f * 1.4426950408889634f;
        const int l = q0w + lq;
        const unsigned short* qp = qkv + (size_t)(b*SEQ + l)*QKP + h*HD + (hi<<3);
        #pragma unroll
        for (int ks = 0; ks < 8; ++ks)
            qf[ks] = *reinterpret_cast<const bf16x8*>(qp + (ks<<4));
        #pragma unroll
        for (int ks = 0; ks < 4; ++ks){
            const int d0 = (ks<<4) + (hi<<3);
            const float4 c0 = *reinterpret_cast<const float4*>(ct + l*HD + d0);
            const float4 c1 = *reinterpret_cast<const float4*>(ct + l*HD + d0 + 4);
            const float4 s0 = *reinterpret_cast<const float4*>(st + l*HD + d0);
            const float4 s1 = *reinterpret_cast<const float4*>(st + l*HD + d0 + 4);
            const float4 C0 = *reinterpret_cast<const float4*>(ct + l*HD + d0 + 64);
            const float4 C1 = *reinterpret_cast<const float4*>(ct + l*HD + d0 + 68);
            const float4 S0 = *reinterpret_cast<const float4*>(st + l*HD + d0 + 64);
            const float4 S1 = *reinterpret_cast<const float4*>(st + l*HD + d0 + 68);
            const float cl[8] = {c0.x,c0.y,c0.z,c0.w, c1.x,c1.y,c1.z,c1.w};
            const float sl[8] = {s0.x,s0.y,s0.z,s0.w, s1.x,s1.y,s1.z,s1.w};
            const float cu[8] = {C0.x,C0.y,C0.z,C0.w, C1.x,C1.y,C1.z,C1.w};
            const float su[8] = {S0.x,S0.y,S0.z,S0.w, S1.x,S1.y,S1.z,S1.w};
            #pragma unroll
            for (int j = 0; j < 8; ++j){
                const float x1 = b2f((unsigned short)qf[ks][j]);
                const float x2 = b2f((unsigned short)qf[ks+4][j]);
                qf[ks][j]   = (short)f2b((x1*cl[j] - x2*sl[j]) * qscale);
                qf[ks+4][j] = (short)f2b((x2*cu[j] + x1*su[j]) * qscale);
            }
        }
    }

    float m_run = -3e38f, l_run = 0.f;
    f32x16 oacc[4] = {};

    #define STAGE(pb, kv0) do { \
        _Pragma("unroll") \
        for (int i = 0; i < 4; ++i){ \
            const int kr = (wave<<4) + (i<<2) + (lane>>4); \
            glds16(Kb + (size_t)((kv0) + kr)*QKP + (((lane&15) ^ (kr&7))<<3), \
                   &smem[((pb)<<13) + (((wave<<4) + (i<<2))<<7)]); \
            const int dr = (wave<<5) + (i<<3) + (lane>>3); \
            glds16(Vb + (size_t)dr*SEQ + (kv0) + (((lane&7) ^ (dr&7))<<3), \
                   &smem[16384 + ((pb)<<13) + (((wave<<5) + (i<<3))<<6)]); \
        } \
    } while(0)

    int buf = 0;
    STAGE(0, 0);
    __syncthreads();

    for (int t = 0; t < SEQ/64; ++t){
        if (t < SEQ/64 - 1) STAGE(buf^1, (t+1)*64);

        const unsigned short* Kbuf = &smem[buf<<13];
        const unsigned short* Vbuf = &smem[16384 + (buf<<13)];

        // ---- S = K * Q  (S[kv][q]) ----
        f32x16 st0 = {}, st1 = {};
        __builtin_amdgcn_s_setprio(1);
        #pragma unroll
        for (int ks = 0; ks < 8; ++ks){
            const int col = (((ks<<1) + hi) ^ (lq & 7)) << 3;
            bf16x8 k0 = *reinterpret_cast<const bf16x8*>(&Kbuf[(lq<<7) + col]);
            bf16x8 k1 = *reinterpret_cast<const bf16x8*>(&Kbuf[((32+lq)<<7) + col]);
            st0 = __builtin_amdgcn_mfma_f32_32x32x16_bf16(k0, qf[ks], st0, 0, 0, 0);
            st1 = __builtin_amdgcn_mfma_f32_32x32x16_bf16(k1, qf[ks], st1, 0, 0, 0);
        }
        __builtin_amdgcn_s_setprio(0);

        // ---- online softmax (exp2 domain), per-lane column q ----
        float tmax = st0[0];
        #pragma unroll
        for (int r = 1; r < 16; ++r) tmax = fmaxf(tmax, st0[r]);
        #pragma unroll
        for (int r = 0; r < 16; ++r) tmax = fmaxf(tmax, st1[r]);
        tmax = fmaxf(tmax, __shfl_xor(tmax, 32));

        // defer-max (T13): skip rescale when max growth small (P bounded by 2^8)
        const bool defer = __all(tmax <= m_run + 8.0f);
        if (!defer){
            const float mnew = fmaxf(m_run, tmax);
            const float al = __builtin_amdgcn_exp2f(m_run - mnew);
            m_run = mnew;
            l_run *= al;
            #pragma unroll
            for (int dt = 0; dt < 4; ++dt) oacc[dt] *= al;
        }
        float tsum = 0.f;
        #pragma unroll
        for (int r = 0; r < 16; ++r){ float p = __builtin_amdgcn_exp2f(st0[r] - m_run); st0[r] = p; tsum += p; }
        #pragma unroll
        for (int r = 0; r < 16; ++r){ float p = __builtin_amdgcn_exp2f(st1[r] - m_run); st1[r] = p; tsum += p; }
        tsum += __shfl_xor(tsum, 32);
        l_run += tsum;

        // ---- P -> B-fragments via pack + permlane32_swap (T12) ----
        bf16x8 pf[4];
        #define MAKEPF(dA, dB, SV) do { \
            unsigned int a0 = pkbf(SV[0],SV[1]),  b0 = pkbf(SV[2],SV[3]); \
            unsigned int c0 = pkbf(SV[4],SV[5]),  d0 = pkbf(SV[6],SV[7]); \
            unsigned int a1 = pkbf(SV[8],SV[9]),  b1 = pkbf(SV[10],SV[11]); \
            unsigned int c1 = pkbf(SV[12],SV[13]),d1 = pkbf(SV[14],SV[15]); \
            asm("v_permlane32_swap_b32 %0, %1" : "+v"(a0), "+v"(c0)); \
            asm("v_permlane32_swap_b32 %0, %1" : "+v"(b0), "+v"(d0)); \
            asm("v_permlane32_swap_b32 %0, %1" : "+v"(a1), "+v"(c1)); \
            asm("v_permlane32_swap_b32 %0, %1" : "+v"(b1), "+v"(d1)); \
            U8 u; \
            u.w[0] = a0; u.w[1] = b0; u.w[2] = c0; u.w[3] = d0; dA = u.v; \
            u.w[0] = a1; u.w[1] = b1; u.w[2] = c1; u.w[3] = d1; dB = u.v; \
        } while(0)
        MAKEPF(pf[0], pf[1], st0);
        MAKEPF(pf[2], pf[3], st1);
        #undef MAKEPF

        // ---- O^T += V^T * P ----
        __builtin_amdgcn_s_setprio(1);
        #pragma unroll
        for (int dt = 0; dt < 4; ++dt){
            const int rowv = (dt<<5) + lq;
            #pragma unroll
            for (int f = 0; f < 4; ++f){
                const int col = (((f<<1) + hi) ^ (lq & 7)) << 3;
                bf16x8 vf = *reinterpret_cast<const bf16x8*>(&Vbuf[(rowv<<6) + col]);
                oacc[dt] = __builtin_amdgcn_mfma_f32_32x32x16_bf16(vf, pf[f], oacc[dt], 0, 0, 0);
            }
        }
        __builtin_amdgcn_s_setprio(0);

        __syncthreads();
        buf ^= 1;
    }
    #undef STAGE

    // ---- epilogue: O^T -> per-wave LDS transpose (reusing smem) -> coalesced global ----
    const float rl = 1.0f / l_run;
    unsigned short* oL = smem + wave*(32*132);
    #pragma unroll
    for (int dt = 0; dt < 4; ++dt)
        #pragma unroll
        for (int g = 0; g < 4; ++g){
            u16x4 w = { f2b(oacc[dt][g*4+0]*rl), f2b(oacc[dt][g*4+1]*rl),
                        f2b(oacc[dt][g*4+2]*rl), f2b(oacc[dt][g*4+3]*rl) };
            *reinterpret_cast<u16x4*>(&oL[lq*132 + (dt<<5) + (hi<<2) + (g<<3)]) = w;
        }
    #pragma unroll
    for (int i = 0; i < 16; ++i){
        const int q = (i<<1) + hi;
        u16x4 w = *reinterpret_cast<const u16x4*>(&oL[q*132 + (lq<<2)]);
        *reinterpret_cast<u16x4*>(&aout[(size_t)(b*SEQ + q0w + q)*DIMS + h*HD + (lq<<2)]) = w;
    }
}

// ---------------- launcher ----------------

extern "C" void kernel_launch(void* const* d_in, const int* in_sizes, int n_in,
                              void* d_out, int out_size, void* d_ws, size_t ws_size,
                              hipStream_t stream)
{
    const float* x    = (const float*)d_in[0];
    const float* rope = (const float*)d_in[1];
    const float* wq   = (const float*)d_in[2];
    const float* wk   = (const float*)d_in[3];
    const float* wv   = (const float*)d_in[4];
    const float* wo   = (const float*)d_in[5];
    const float* bo   = (const float*)d_in[6];
    float* out = (float*)d_out;

    char* ws = (char*)d_ws;
    unsigned short* x_bf   = (unsigned short*)(ws + 0);            // 16.8 MB
    unsigned short* wqkv   = (unsigned short*)(ws + 16777216);     // 25.2 MB
    unsigned short* wo_bf  = (unsigned short*)(ws + 41943040);     // 8.4 MB
    float*          cos_t  = (float*)(ws + 50331648);              // 1 MB
    float*          sin_t  = (float*)(ws + 51380224);              // 1 MB
    unsigned short* qkv    = (unsigned short*)(ws + 52428800);     // 33.6 MB (QK only, pitch 4096)
    unsigned short* vt     = (unsigned short*)(ws + 85983232);     // 16.8 MB (ends ~98 MB)
    unsigned short* a_out  = (unsigned short*)(ws + 0);            // alias x_bf (dead after QKV GEMM)

    // 1. fused prep: x->bf16, 4 weights->bf16, cos/sin
    k_prep<<<dim3(4096, 7), 256, 0, stream>>>(x, wq, wk, wv, wo, rope,
                                              x_bf, wqkv, wqkv + 4194304, wqkv + 8388608, wo_bf,
                                              cos_t, sin_t);

    // 2. QKV projection with fused epilogue: Q plain, K roped (2-pass stash), V transposed->vt
    k_gemm_bt<0><<<(MROWS/128)*(QKVN/128), 256, 0, stream>>>(
        x_bf, wqkv, qkv, nullptr, vt, cos_t, sin_t, MROWS, QKVN, DIMS, QKP);

    // 3. attention (Q-rope in-register): 512 blocks = 2/CU x 256 CUs
    k_attn<<<dim3(SEQ/128, BATCH*HEADS), 256, 0, stream>>>(qkv, vt, cos_t, sin_t, a_out);

    // 4. output projection + bias
    k_gemm_bt<1><<<(MROWS/128)*(DIMS/128), 256, 0, stream>>>(
        a_out, wo_bf, out, bo, nullptr, nullptr, nullptr, MROWS, DIMS, DIMS, DIMS);
}

// Round 11
// 285.407 us; speedup vs baseline: 1.0166x; 1.0166x over previous
//
#include <hip/hip_runtime.h>
#include <hip/hip_bf16.h>
#include <stdint.h>

// Problem constants
#define DIMS  2048
#define HEADS 16
#define HD    128
#define BATCH 2
#define SEQ   2048
#define MROWS (BATCH*SEQ)   // 4096
#define QKVN  (3*DIMS)      // 6144

using bf16x8 = __attribute__((ext_vector_type(8))) short;
using f32x4  = __attribute__((ext_vector_type(4))) float;
using f32x16 = __attribute__((ext_vector_type(16))) float;
using u16x4  = __attribute__((ext_vector_type(4))) unsigned short;

__device__ __forceinline__ unsigned short f2b(float f){
    __hip_bfloat16 h = __float2bfloat16(f);
    return *reinterpret_cast<unsigned short*>(&h);
}
__device__ __forceinline__ float b2f(unsigned short u){
    __hip_bfloat16 h;
    *reinterpret_cast<unsigned short*>(&h) = u;
    return __bfloat162float(h);
}
__device__ __forceinline__ unsigned int pkbf(float lo, float hi){
    return (unsigned int)f2b(lo) | ((unsigned int)f2b(hi) << 16);
}

// async global->LDS, 16B per lane. LDS dest is wave-uniform base (+lane*16 implicit).
__device__ __forceinline__ void glds16(const void* g, void* l){
    __builtin_amdgcn_global_load_lds(
        (const __attribute__((address_space(1))) unsigned int*)g,
        (__attribute__((address_space(3))) unsigned int*)l, 16, 0, 0);
}

// ---------------- fused prep: x->bf16, 4x w->bf16, cos/sin table ----------------
// grid (4096, 7): y 0..3 -> weight y; y 4..5 -> x halves; y 6 -> cossin (1024 blocks active)

__global__ void k_prep(const float* __restrict__ x,
                       const float* __restrict__ w0, const float* __restrict__ w1,
                       const float* __restrict__ w2, const float* __restrict__ w3,
                       const float* __restrict__ rope,
                       unsigned short* __restrict__ x_bf,
                       unsigned short* __restrict__ d0, unsigned short* __restrict__ d1,
                       unsigned short* __restrict__ d2, unsigned short* __restrict__ d3,
                       float* __restrict__ ct, float* __restrict__ st){
    const int y = blockIdx.y;
    if (y == 6){
        const int i = blockIdx.x*blockDim.x + threadIdx.x;
        if (i >= SEQ*HD) return;
        const float v = rope[i];
        ct[i] = cosf(v);
        st[i] = sinf(v);
        return;
    }
    const float* src;
    unsigned short* dst;
    size_t off = 0;
    if      (y == 0){ src = w0; dst = d0; }
    else if (y == 1){ src = w1; dst = d1; }
    else if (y == 2){ src = w2; dst = d2; }
    else if (y == 3){ src = w3; dst = d3; }
    else            { src = x;  dst = x_bf; off = (size_t)(y - 4) * 1048576; }
    const size_t i = off + blockIdx.x*blockDim.x + threadIdx.x;
    const float4 v = reinterpret_cast<const float4*>(src)[i];
    u16x4 o = { f2b(v.x), f2b(v.y), f2b(v.z), f2b(v.w) };
    *reinterpret_cast<u16x4*>(dst + 4*i) = o;
}

// ---------------- fused K-rope + V-transpose ----------------
// grid 4096 x 256. bid < 2048: RoPE in-place on K section (bf16x8 vectorized).
// bid >= 2048: V transpose qkv[b][l][2*DIMS + h*128+d] -> vt[(b*16+h)*128+d][l].
// NOTE (R9/R10 lesson): fusing these into the GEMM epilogue regressed twice —
// LDS +1KB cost a blocks/CU step (R9), multi-region epilogue cost +32 VGPR (R10).
// The m97 GEMM plateau depends on its lean 76-VGPR / 32KB-LDS body; keep this separate.

__global__ void k_kropevt(unsigned short* __restrict__ qkv,
                          const float* __restrict__ ct, const float* __restrict__ st,
                          unsigned short* __restrict__ vt){
    __shared__ unsigned short t[64*68];
    const int bid = blockIdx.x;
    if (bid < 2048){
        const int idx = bid*blockDim.x + threadIdx.x;   // 524288
        const int d0 = (idx & 7) << 3;
        const int h  = (idx >> 3) & (HEADS-1);
        const int l  = (idx >> 7) & (SEQ-1);
        const int b  = idx >> 18;
        const float4* cp = reinterpret_cast<const float4*>(ct + l*HD + d0);
        const float4* sp = reinterpret_cast<const float4*>(st + l*HD + d0);
        const float4 cl0 = cp[0],  cl1 = cp[1];
        const float4 sl0 = sp[0],  sl1 = sp[1];
        const float4 cu0 = cp[16], cu1 = cp[17];
        const float4 su0 = sp[16], su1 = sp[17];
        const float cl[8] = {cl0.x,cl0.y,cl0.z,cl0.w, cl1.x,cl1.y,cl1.z,cl1.w};
        const float sl[8] = {sl0.x,sl0.y,sl0.z,sl0.w, sl1.x,sl1.y,sl1.z,sl1.w};
        const float cu[8] = {cu0.x,cu0.y,cu0.z,cu0.w, cu1.x,cu1.y,cu1.z,cu1.w};
        const float su[8] = {su0.x,su0.y,su0.z,su0.w, su1.x,su1.y,su1.z,su1.w};
        unsigned short* rp = qkv + (size_t)(b*SEQ + l)*QKVN + DIMS + h*HD + d0;  // K section
        bf16x8 lo = *reinterpret_cast<const bf16x8*>(rp);
        bf16x8 hi = *reinterpret_cast<const bf16x8*>(rp + 64);
        bf16x8 olo, ohi;
        #pragma unroll
        for (int j = 0; j < 8; ++j){
            const float x1 = b2f((unsigned short)lo[j]);
            const float x2 = b2f((unsigned short)hi[j]);
            olo[j] = (short)f2b(x1*cl[j] - x2*sl[j]);
            ohi[j] = (short)f2b(x2*cu[j] + x1*su[j]);
        }
        *reinterpret_cast<bf16x8*>(rp)      = olo;
        *reinterpret_cast<bf16x8*>(rp + 64) = ohi;
        return;
    }
    // ---- V transpose ----
    const int bid2 = bid - 2048;
    const int lt = bid2 & 31;
    const int dt = (bid2 >> 5) & 1;
    const int bh = bid2 >> 6;
    const int b = bh >> 4, h = bh & 15;
    const int tid = threadIdx.x;
    const int l0 = lt << 6;
    #pragma unroll
    for (int it = 0; it < 4; ++it){
        const int c = tid + (it<<8);
        const int l = c >> 4;
        const int d4 = (c & 15) << 2;
        const u16x4 v = *reinterpret_cast<const u16x4*>(
            qkv + (size_t)(b*SEQ + l0 + l)*QKVN + 2*DIMS + h*HD + (dt<<6) + d4);
        *reinterpret_cast<u16x4*>(&t[l*68 + d4]) = v;
    }
    __syncthreads();
    #pragma unroll
    for (int it = 0; it < 4; ++it){
        const int c = tid + (it<<8);
        const int d = c >> 4;
        const int l4 = (c & 15) << 2;
        u16x4 o = { t[(l4+0)*68 + d], t[(l4+1)*68 + d], t[(l4+2)*68 + d], t[(l4+3)*68 + d] };
        *reinterpret_cast<u16x4*>(&vt[((size_t)bh*HD + (dt<<6) + d)*SEQ + l0 + l4]) = o;
    }
}

// ---------------- 128x128 GEMM (m97 structure) — both projections ----------------

template<int FINAL>
__global__ __launch_bounds__(256) void k_gemm_bt(
    const unsigned short* __restrict__ A, const unsigned short* __restrict__ B,
    void* __restrict__ C, const float* __restrict__ bias, int M, int N, int K)
{
    __shared__ unsigned short lA[128*64];
    __shared__ unsigned short lB[128*64];
    const int tid  = threadIdx.x;
    const int lane = tid & 63;
    const int wave = tid >> 6;

    const int nbx = N >> 7;
    const int nwg = gridDim.x;
    const int cpx = nwg >> 3;
    const int bid = blockIdx.x;
    const int wg  = (bid & 7)*cpx + (bid >> 3);
    const int m0 = (wg / nbx) << 7;
    const int n0 = (wg % nbx) << 7;

    const int wr = (wave >> 1) << 6;
    const int wc = (wave & 1) << 6;

    f32x4 acc[4][4] = {};

    const int srow_base = (wave<<3) + (lane>>3);
    const int schunk = lane & 7;

    for (int k0 = 0; k0 < K; k0 += 64){
        #pragma unroll
        for (int i = 0; i < 4; ++i){
            const int row  = (i<<5) + srow_base;
            const int scol = k0 + ((schunk ^ (row & 7)) << 3);
            glds16(A + (size_t)(m0 + row)*K + scol, &lA[((i<<5) + (wave<<3)) << 6]);
            glds16(B + (size_t)(n0 + row)*K + scol, &lB[((i<<5) + (wave<<3)) << 6]);
        }
        __syncthreads();
        #pragma unroll
        for (int ks = 0; ks < 2; ++ks){
            bf16x8 af[4], bfr[4];
            const int colbase = (ks<<5) + ((lane>>4)<<3);
            #pragma unroll
            for (int mi = 0; mi < 4; ++mi){
                const int row = wr + (mi<<4) + (lane & 15);
                af[mi] = *reinterpret_cast<const bf16x8*>(&lA[(row<<6) + (colbase ^ ((row&7)<<3))]);
            }
            #pragma unroll
            for (int ni = 0; ni < 4; ++ni){
                const int row = wc + (ni<<4) + (lane & 15);
                bfr[ni] = *reinterpret_cast<const bf16x8*>(&lB[(row<<6) + (colbase ^ ((row&7)<<3))]);
            }
            #pragma unroll
            for (int mi = 0; mi < 4; ++mi)
                #pragma unroll
                for (int ni = 0; ni < 4; ++ni)
                    acc[mi][ni] = __builtin_amdgcn_mfma_f32_16x16x32_bf16(af[mi], bfr[ni], acc[mi][ni], 0, 0, 0);
        }
        __syncthreads();
    }

    const int r0 = (lane >> 4) << 2;
    const int cn = lane & 15;
    #pragma unroll
    for (int mi = 0; mi < 4; ++mi)
        #pragma unroll
        for (int r = 0; r < 4; ++r){
            const int gm = m0 + wr + (mi<<4) + r0 + r;
            #pragma unroll
            for (int ni = 0; ni < 4; ++ni){
                const int gn = n0 + wc + (ni<<4) + cn;
                const float v = acc[mi][ni][r];
                if (FINAL)
                    reinterpret_cast<float*>(C)[(size_t)gm*N + gn] = v + bias[gn];
                else
                    reinterpret_cast<unsigned short*>(C)[(size_t)gm*N + gn] = f2b(v);
            }
        }
}

// ---------------- flash attention, swapped-operand 32x32, 4-wave blocks ----------------
// grid (SEQ/128=16, bh=32), block 256 (4 waves x 32 q-rows). KV tile 64, dbuf.
// Q-rope applied in-register at Q-load (pairs (d, d+64) = (qf[ks][j], qf[ks+4][j])).
// LDS union 64KB; 2 blocks/CU, 512 blocks = 1 full round.

union U8 { unsigned int w[4]; bf16x8 v; };

__global__ __launch_bounds__(256, 2) void k_attn(
    const unsigned short* __restrict__ qkv, const unsigned short* __restrict__ vt,
    const float* __restrict__ ct, const float* __restrict__ st,
    unsigned short* __restrict__ aout)
{
    __shared__ unsigned short smem[32768];   // 64 KB

    const int tid  = threadIdx.x;
    const int lane = tid & 63;
    const int wave = tid >> 6;               // 0..3
    const int lq   = lane & 31;
    const int hi   = lane >> 5;
    const int bh = blockIdx.y;
    const int b = bh >> 4, h = bh & 15;
    const int q0w = (blockIdx.x << 7) + (wave << 5);

    const unsigned short* Kb = qkv + (size_t)b*SEQ*QKVN + DIMS + h*HD;
    const unsigned short* Vb = vt + (size_t)bh*HD*SEQ;

    // Q fragments (B-operand: col=q=lane&31, k=hi*8+j) with in-register RoPE,
    // pre-scaled by log2e/sqrt(HD). d(ks,j) = ks*16 + hi*8 + j; pair = qf[ks+4][j].
    bf16x8 qf[8];
    {
        const float qscale = 0.08838834764831845f * 1.4426950408889634f;
        const int l = q0w + lq;
        const unsigned short* qp = qkv + (size_t)(b*SEQ + l)*QKVN + h*HD + (hi<<3);
        #pragma unroll
        for (int ks = 0; ks < 8; ++ks)
            qf[ks] = *reinterpret_cast<const bf16x8*>(qp + (ks<<4));
        #pragma unroll
        for (int ks = 0; ks < 4; ++ks){
            const int d0 = (ks<<4) + (hi<<3);
            const float4 c0 = *reinterpret_cast<const float4*>(ct + l*HD + d0);
            const float4 c1 = *reinterpret_cast<const float4*>(ct + l*HD + d0 + 4);
            const float4 s0 = *reinterpret_cast<const float4*>(st + l*HD + d0);
            const float4 s1 = *reinterpret_cast<const float4*>(st + l*HD + d0 + 4);
            const float4 C0 = *reinterpret_cast<const float4*>(ct + l*HD + d0 + 64);
            const float4 C1 = *reinterpret_cast<const float4*>(ct + l*HD + d0 + 68);
            const float4 S0 = *reinterpret_cast<const float4*>(st + l*HD + d0 + 64);
            const float4 S1 = *reinterpret_cast<const float4*>(st + l*HD + d0 + 68);
            const float cl[8] = {c0.x,c0.y,c0.z,c0.w, c1.x,c1.y,c1.z,c1.w};
            const float sl[8] = {s0.x,s0.y,s0.z,s0.w, s1.x,s1.y,s1.z,s1.w};
            const float cu[8] = {C0.x,C0.y,C0.z,C0.w, C1.x,C1.y,C1.z,C1.w};
            const float su[8] = {S0.x,S0.y,S0.z,S0.w, S1.x,S1.y,S1.z,S1.w};
            #pragma unroll
            for (int j = 0; j < 8; ++j){
                const float x1 = b2f((unsigned short)qf[ks][j]);
                const float x2 = b2f((unsigned short)qf[ks+4][j]);
                qf[ks][j]   = (short)f2b((x1*cl[j] - x2*sl[j]) * qscale);
                qf[ks+4][j] = (short)f2b((x2*cu[j] + x1*su[j]) * qscale);
            }
        }
    }

    float m_run = -3e38f, l_run = 0.f;
    f32x16 oacc[4] = {};

    #define STAGE(pb, kv0) do { \
        _Pragma("unroll") \
        for (int i = 0; i < 4; ++i){ \
            const int kr = (wave<<4) + (i<<2) + (lane>>4); \
            glds16(Kb + (size_t)((kv0) + kr)*QKVN + (((lane&15) ^ (kr&7))<<3), \
                   &smem[((pb)<<13) + (((wave<<4) + (i<<2))<<7)]); \
            const int dr = (wave<<5) + (i<<3) + (lane>>3); \
            glds16(Vb + (size_t)dr*SEQ + (kv0) + (((lane&7) ^ (dr&7))<<3), \
                   &smem[16384 + ((pb)<<13) + (((wave<<5) + (i<<3))<<6)]); \
        } \
    } while(0)

    int buf = 0;
    STAGE(0, 0);
    __syncthreads();

    for (int t = 0; t < SEQ/64; ++t){
        if (t < SEQ/64 - 1) STAGE(buf^1, (t+1)*64);

        const unsigned short* Kbuf = &smem[buf<<13];
        const unsigned short* Vbuf = &smem[16384 + (buf<<13)];

        // ---- S = K * Q  (S[kv][q]) ----
        f32x16 st0 = {}, st1 = {};
        __builtin_amdgcn_s_setprio(1);
        #pragma unroll
        for (int ks = 0; ks < 8; ++ks){
            const int col = (((ks<<1) + hi) ^ (lq & 7)) << 3;
            bf16x8 k0 = *reinterpret_cast<const bf16x8*>(&Kbuf[(lq<<7) + col]);
            bf16x8 k1 = *reinterpret_cast<const bf16x8*>(&Kbuf[((32+lq)<<7) + col]);
            st0 = __builtin_amdgcn_mfma_f32_32x32x16_bf16(k0, qf[ks], st0, 0, 0, 0);
            st1 = __builtin_amdgcn_mfma_f32_32x32x16_bf16(k1, qf[ks], st1, 0, 0, 0);
        }
        __builtin_amdgcn_s_setprio(0);

        // ---- online softmax (exp2 domain), per-lane column q ----
        float tmax = st0[0];
        #pragma unroll
        for (int r = 1; r < 16; ++r) tmax = fmaxf(tmax, st0[r]);
        #pragma unroll
        for (int r = 0; r < 16; ++r) tmax = fmaxf(tmax, st1[r]);
        tmax = fmaxf(tmax, __shfl_xor(tmax, 32));

        // defer-max (T13): skip rescale when max growth small (P bounded by 2^8)
        const bool defer = __all(tmax <= m_run + 8.0f);
        if (!defer){
            const float mnew = fmaxf(m_run, tmax);
            const float al = __builtin_amdgcn_exp2f(m_run - mnew);
            m_run = mnew;
            l_run *= al;
            #pragma unroll
            for (int dt = 0; dt < 4; ++dt) oacc[dt] *= al;
        }
        float tsum = 0.f;
        #pragma unroll
        for (int r = 0; r < 16; ++r){ float p = __builtin_amdgcn_exp2f(st0[r] - m_run); st0[r] = p; tsum += p; }
        #pragma unroll
        for (int r = 0; r < 16; ++r){ float p = __builtin_amdgcn_exp2f(st1[r] - m_run); st1[r] = p; tsum += p; }
        tsum += __shfl_xor(tsum, 32);
        l_run += tsum;

        // ---- P -> B-fragments via pack + permlane32_swap (T12) ----
        bf16x8 pf[4];
        #define MAKEPF(dA, dB, SV) do { \
            unsigned int a0 = pkbf(SV[0],SV[1]),  b0 = pkbf(SV[2],SV[3]); \
            unsigned int c0 = pkbf(SV[4],SV[5]),  d0 = pkbf(SV[6],SV[7]); \
            unsigned int a1 = pkbf(SV[8],SV[9]),  b1 = pkbf(SV[10],SV[11]); \
            unsigned int c1 = pkbf(SV[12],SV[13]),d1 = pkbf(SV[14],SV[15]); \
            asm("v_permlane32_swap_b32 %0, %1" : "+v"(a0), "+v"(c0)); \
            asm("v_permlane32_swap_b32 %0, %1" : "+v"(b0), "+v"(d0)); \
            asm("v_permlane32_swap_b32 %0, %1" : "+v"(a1), "+v"(c1)); \
            asm("v_permlane32_swap_b32 %0, %1" : "+v"(b1), "+v"(d1)); \
            U8 u; \
            u.w[0] = a0; u.w[1] = b0; u.w[2] = c0; u.w[3] = d0; dA = u.v; \
            u.w[0] = a1; u.w[1] = b1; u.w[2] = c1; u.w[3] = d1; dB = u.v; \
        } while(0)
        MAKEPF(pf[0], pf[1], st0);
        MAKEPF(pf[2], pf[3], st1);
        #undef MAKEPF

        // ---- O^T += V^T * P ----
        __builtin_amdgcn_s_setprio(1);
        #pragma unroll
        for (int dt = 0; dt < 4; ++dt){
            const int rowv = (dt<<5) + lq;
            #pragma unroll
            for (int f = 0; f < 4; ++f){
                const int col = (((f<<1) + hi) ^ (lq & 7)) << 3;
                bf16x8 vf = *reinterpret_cast<const bf16x8*>(&Vbuf[(rowv<<6) + col]);
                oacc[dt] = __builtin_amdgcn_mfma_f32_32x32x16_bf16(vf, pf[f], oacc[dt], 0, 0, 0);
            }
        }
        __builtin_amdgcn_s_setprio(0);

        __syncthreads();
        buf ^= 1;
    }
    #undef STAGE

    // ---- epilogue: O^T -> per-wave LDS transpose (reusing smem) -> coalesced global ----
    const float rl = 1.0f / l_run;
    unsigned short* oL = smem + wave*(32*132);
    #pragma unroll
    for (int dt = 0; dt < 4; ++dt)
        #pragma unroll
        for (int g = 0; g < 4; ++g){
            u16x4 w = { f2b(oacc[dt][g*4+0]*rl), f2b(oacc[dt][g*4+1]*rl),
                        f2b(oacc[dt][g*4+2]*rl), f2b(oacc[dt][g*4+3]*rl) };
            *reinterpret_cast<u16x4*>(&oL[lq*132 + (dt<<5) + (hi<<2) + (g<<3)]) = w;
        }
    #pragma unroll
    for (int i = 0; i < 16; ++i){
        const int q = (i<<1) + hi;
        u16x4 w = *reinterpret_cast<const u16x4*>(&oL[q*132 + (lq<<2)]);
        *reinterpret_cast<u16x4*>(&aout[(size_t)(b*SEQ + q0w + q)*DIMS + h*HD + (lq<<2)]) = w;
    }
}

// ---------------- launcher ----------------

extern "C" void kernel_launch(void* const* d_in, const int* in_sizes, int n_in,
                              void* d_out, int out_size, void* d_ws, size_t ws_size,
                              hipStream_t stream)
{
    const float* x    = (const float*)d_in[0];
    const float* rope = (const float*)d_in[1];
    const float* wq   = (const float*)d_in[2];
    const float* wk   = (const float*)d_in[3];
    const float* wv   = (const float*)d_in[4];
    const float* wo   = (const float*)d_in[5];
    const float* bo   = (const float*)d_in[6];
    float* out = (float*)d_out;

    char* ws = (char*)d_ws;
    unsigned short* x_bf   = (unsigned short*)(ws + 0);            // 16.8 MB
    unsigned short* wqkv   = (unsigned short*)(ws + 16777216);     // 25.2 MB
    unsigned short* wo_bf  = (unsigned short*)(ws + 41943040);     // 8.4 MB
    float*          cos_t  = (float*)(ws + 50331648);              // 1 MB
    float*          sin_t  = (float*)(ws + 51380224);              // 1 MB
    unsigned short* qkv    = (unsigned short*)(ws + 52428800);     // 50.3 MB
    unsigned short* vt     = (unsigned short*)(ws + 16777216);     // alias wqkv (dead after QKV GEMM)
    unsigned short* a_out  = (unsigned short*)(ws + 0);            // alias x_bf (dead after QKV GEMM)

    // 1. fused prep: x->bf16, 4 weights->bf16, cos/sin
    k_prep<<<dim3(4096, 7), 256, 0, stream>>>(x, wq, wk, wv, wo, rope,
                                              x_bf, wqkv, wqkv + 4194304, wqkv + 8388608, wo_bf,
                                              cos_t, sin_t);

    // 2. QKV projection: m97 128^2 kernel, grid 32*48 = 1536
    k_gemm_bt<0><<<(MROWS/128)*(QKVN/128), 256, 0, stream>>>(x_bf, wqkv, qkv, nullptr, MROWS, QKVN, DIMS);

    // 3. fused K-rope (in place) + V transpose
    k_kropevt<<<4096, 256, 0, stream>>>(qkv, cos_t, sin_t, vt);

    // 4. attention (Q-rope in-register): 512 blocks = 2/CU x 256 CUs
    k_attn<<<dim3(SEQ/128, BATCH*HEADS), 256, 0, stream>>>(qkv, vt, cos_t, sin_t, a_out);

    // 5. output projection + bias
    k_gemm_bt<1><<<(MROWS/128)*(DIMS/128), 256, 0, stream>>>(a_out, wo_bf, out, bo, MROWS, DIMS, DIMS);
}

// Round 12
// 278.297 us; speedup vs baseline: 1.0425x; 1.0255x over previous
//
#include <hip/hip_runtime.h>
#include <hip/hip_bf16.h>
#include <stdint.h>

// Problem constants
#define DIMS  2048
#define HEADS 16
#define HD    128
#define BATCH 2
#define SEQ   2048
#define MROWS (BATCH*SEQ)   // 4096
#define QKVN  (3*DIMS)      // 6144

using bf16x8 = __attribute__((ext_vector_type(8))) short;
using f32x4  = __attribute__((ext_vector_type(4))) float;
using f32x16 = __attribute__((ext_vector_type(16))) float;
using u16x4  = __attribute__((ext_vector_type(4))) unsigned short;

__device__ __forceinline__ unsigned short f2b(float f){
    __hip_bfloat16 h = __float2bfloat16(f);
    return *reinterpret_cast<unsigned short*>(&h);
}
__device__ __forceinline__ float b2f(unsigned short u){
    __hip_bfloat16 h;
    *reinterpret_cast<unsigned short*>(&h) = u;
    return __bfloat162float(h);
}
__device__ __forceinline__ unsigned int pkbf(float lo, float hi){
    return (unsigned int)f2b(lo) | ((unsigned int)f2b(hi) << 16);
}

// async global->LDS, 16B per lane. LDS dest is wave-uniform base (+lane*16 implicit).
__device__ __forceinline__ void glds16(const void* g, void* l){
    __builtin_amdgcn_global_load_lds(
        (const __attribute__((address_space(1))) unsigned int*)g,
        (__attribute__((address_space(3))) unsigned int*)l, 16, 0, 0);
}

// ---------------- fused prep: x->bf16, 4x w->bf16, cos/sin table ----------------
// grid (4096, 7): y 0..3 -> weight y; y 4..5 -> x halves; y 6 -> cossin (1024 blocks active)

__global__ void k_prep(const float* __restrict__ x,
                       const float* __restrict__ w0, const float* __restrict__ w1,
                       const float* __restrict__ w2, const float* __restrict__ w3,
                       const float* __restrict__ rope,
                       unsigned short* __restrict__ x_bf,
                       unsigned short* __restrict__ d0, unsigned short* __restrict__ d1,
                       unsigned short* __restrict__ d2, unsigned short* __restrict__ d3,
                       float* __restrict__ ct, float* __restrict__ st){
    const int y = blockIdx.y;
    if (y == 6){
        const int i = blockIdx.x*blockDim.x + threadIdx.x;
        if (i >= SEQ*HD) return;
        const float v = rope[i];
        ct[i] = cosf(v);
        st[i] = sinf(v);
        return;
    }
    const float* src;
    unsigned short* dst;
    size_t off = 0;
    if      (y == 0){ src = w0; dst = d0; }
    else if (y == 1){ src = w1; dst = d1; }
    else if (y == 2){ src = w2; dst = d2; }
    else if (y == 3){ src = w3; dst = d3; }
    else            { src = x;  dst = x_bf; off = (size_t)(y - 4) * 1048576; }
    const size_t i = off + blockIdx.x*blockDim.x + threadIdx.x;
    const float4 v = reinterpret_cast<const float4*>(src)[i];
    u16x4 o = { f2b(v.x), f2b(v.y), f2b(v.z), f2b(v.w) };
    *reinterpret_cast<u16x4*>(dst + 4*i) = o;
}

// ---------------- fused K-rope + V-transpose ----------------
// grid 4096 x 256. bid < 2048: RoPE in-place on K section (bf16x8 vectorized).
// bid >= 2048: V transpose qkv[b][l][2*DIMS + h*128+d] -> vt[(b*16+h)*128+d][l].
// NOTE (R9/R10 lesson): fusing these into the GEMM epilogue regressed twice —
// LDS +1KB cost a blocks/CU step (R9), multi-region epilogue cost +32 VGPR (R10).
// The m97 GEMM plateau depends on its lean 76-VGPR / 32KB-LDS body; keep this separate.

__global__ void k_kropevt(unsigned short* __restrict__ qkv,
                          const float* __restrict__ ct, const float* __restrict__ st,
                          unsigned short* __restrict__ vt){
    __shared__ unsigned short t[64*68];
    const int bid = blockIdx.x;
    if (bid < 2048){
        const int idx = bid*blockDim.x + threadIdx.x;   // 524288
        const int d0 = (idx & 7) << 3;
        const int h  = (idx >> 3) & (HEADS-1);
        const int l  = (idx >> 7) & (SEQ-1);
        const int b  = idx >> 18;
        const float4* cp = reinterpret_cast<const float4*>(ct + l*HD + d0);
        const float4* sp = reinterpret_cast<const float4*>(st + l*HD + d0);
        const float4 cl0 = cp[0],  cl1 = cp[1];
        const float4 sl0 = sp[0],  sl1 = sp[1];
        const float4 cu0 = cp[16], cu1 = cp[17];
        const float4 su0 = sp[16], su1 = sp[17];
        const float cl[8] = {cl0.x,cl0.y,cl0.z,cl0.w, cl1.x,cl1.y,cl1.z,cl1.w};
        const float sl[8] = {sl0.x,sl0.y,sl0.z,sl0.w, sl1.x,sl1.y,sl1.z,sl1.w};
        const float cu[8] = {cu0.x,cu0.y,cu0.z,cu0.w, cu1.x,cu1.y,cu1.z,cu1.w};
        const float su[8] = {su0.x,su0.y,su0.z,su0.w, su1.x,su1.y,su1.z,su1.w};
        unsigned short* rp = qkv + (size_t)(b*SEQ + l)*QKVN + DIMS + h*HD + d0;  // K section
        bf16x8 lo = *reinterpret_cast<const bf16x8*>(rp);
        bf16x8 hi = *reinterpret_cast<const bf16x8*>(rp + 64);
        bf16x8 olo, ohi;
        #pragma unroll
        for (int j = 0; j < 8; ++j){
            const float x1 = b2f((unsigned short)lo[j]);
            const float x2 = b2f((unsigned short)hi[j]);
            olo[j] = (short)f2b(x1*cl[j] - x2*sl[j]);
            ohi[j] = (short)f2b(x2*cu[j] + x1*su[j]);
        }
        *reinterpret_cast<bf16x8*>(rp)      = olo;
        *reinterpret_cast<bf16x8*>(rp + 64) = ohi;
        return;
    }
    // ---- V transpose ----
    const int bid2 = bid - 2048;
    const int lt = bid2 & 31;
    const int dt = (bid2 >> 5) & 1;
    const int bh = bid2 >> 6;
    const int b = bh >> 4, h = bh & 15;
    const int tid = threadIdx.x;
    const int l0 = lt << 6;
    #pragma unroll
    for (int it = 0; it < 4; ++it){
        const int c = tid + (it<<8);
        const int l = c >> 4;
        const int d4 = (c & 15) << 2;
        const u16x4 v = *reinterpret_cast<const u16x4*>(
            qkv + (size_t)(b*SEQ + l0 + l)*QKVN + 2*DIMS + h*HD + (dt<<6) + d4);
        *reinterpret_cast<u16x4*>(&t[l*68 + d4]) = v;
    }
    __syncthreads();
    #pragma unroll
    for (int it = 0; it < 4; ++it){
        const int c = tid + (it<<8);
        const int d = c >> 4;
        const int l4 = (c & 15) << 2;
        u16x4 o = { t[(l4+0)*68 + d], t[(l4+1)*68 + d], t[(l4+2)*68 + d], t[(l4+3)*68 + d] };
        *reinterpret_cast<u16x4*>(&vt[((size_t)bh*HD + (dt<<6) + d)*SEQ + l0 + l4]) = o;
    }
}

// ---------------- 128x128 GEMM (m97 staging) with 32x32x16 MFMA ----------------
// Change vs R11: inner compute uses mfma_f32_32x32x16_bf16 (2495 TF unit vs 2075,
// half the MFMA instruction count) — fragment mappings identical to the ones
// session-verified in k_attn. Staging/swizzle/XCD/LDS unchanged (lean body).
// Per wave: 64x64 output = 2x2 tiles of 32x32, f32x16 acc each (64 VGPRs, same).

template<int FINAL>
__global__ __launch_bounds__(256) void k_gemm_bt(
    const unsigned short* __restrict__ A, const unsigned short* __restrict__ B,
    void* __restrict__ C, const float* __restrict__ bias, int M, int N, int K)
{
    __shared__ unsigned short lA[128*64];
    __shared__ unsigned short lB[128*64];
    const int tid  = threadIdx.x;
    const int lane = tid & 63;
    const int wave = tid >> 6;
    const int lq   = lane & 31;
    const int hi   = lane >> 5;

    const int nbx = N >> 7;
    const int nwg = gridDim.x;
    const int cpx = nwg >> 3;
    const int bid = blockIdx.x;
    const int wg  = (bid & 7)*cpx + (bid >> 3);
    const int m0 = (wg / nbx) << 7;
    const int n0 = (wg % nbx) << 7;

    const int wr = (wave >> 1) << 6;
    const int wc = (wave & 1) << 6;

    f32x16 acc[2][2] = {};

    const int srow_base = (wave<<3) + (lane>>3);
    const int schunk = lane & 7;

    for (int k0 = 0; k0 < K; k0 += 64){
        #pragma unroll
        for (int i = 0; i < 4; ++i){
            const int row  = (i<<5) + srow_base;
            const int scol = k0 + ((schunk ^ (row & 7)) << 3);
            glds16(A + (size_t)(m0 + row)*K + scol, &lA[((i<<5) + (wave<<3)) << 6]);
            glds16(B + (size_t)(n0 + row)*K + scol, &lB[((i<<5) + (wave<<3)) << 6]);
        }
        __syncthreads();
        // 4 K-subtiles of 16; A frag: row=lq, k=hi*8+j -> chunk (ks*2+hi), swizzled ^(row&7)
        #pragma unroll
        for (int ks = 0; ks < 4; ++ks){
            const int c8 = (ks<<1) + hi;
            bf16x8 af[2], bfr[2];
            #pragma unroll
            for (int ti = 0; ti < 2; ++ti){
                const int rowa = wr + (ti<<5) + lq;
                af[ti] = *reinterpret_cast<const bf16x8*>(&lA[(rowa<<6) + ((c8 ^ (rowa&7))<<3)]);
            }
            #pragma unroll
            for (int tj = 0; tj < 2; ++tj){
                const int rowb = wc + (tj<<5) + lq;
                bfr[tj] = *reinterpret_cast<const bf16x8*>(&lB[(rowb<<6) + ((c8 ^ (rowb&7))<<3)]);
            }
            #pragma unroll
            for (int ti = 0; ti < 2; ++ti)
                #pragma unroll
                for (int tj = 0; tj < 2; ++tj)
                    acc[ti][tj] = __builtin_amdgcn_mfma_f32_32x32x16_bf16(af[ti], bfr[tj], acc[ti][tj], 0, 0, 0);
        }
        __syncthreads();
    }

    // epilogue: D layout (32x32): col=lane&31, row=(r&3)+8*(r>>2)+4*(lane>>5)
    #pragma unroll
    for (int ti = 0; ti < 2; ++ti)
        #pragma unroll
        for (int tj = 0; tj < 2; ++tj)
            #pragma unroll
            for (int r = 0; r < 16; ++r){
                const int row = (r&3) + ((r>>2)<<3) + (hi<<2);
                const int gm = m0 + wr + (ti<<5) + row;
                const int gn = n0 + wc + (tj<<5) + lq;
                const float v = acc[ti][tj][r];
                if (FINAL)
                    reinterpret_cast<float*>(C)[(size_t)gm*N + gn] = v + bias[gn];
                else
                    reinterpret_cast<unsigned short*>(C)[(size_t)gm*N + gn] = f2b(v);
            }
}

// ---------------- flash attention, swapped-operand 32x32, 4-wave blocks ----------------
// grid (SEQ/128=16, bh=32), block 256 (4 waves x 32 q-rows). KV tile 64, dbuf.
// Q-rope applied in-register at Q-load (pairs (d, d+64) = (qf[ks][j], qf[ks+4][j])).
// LDS union 64KB; 2 blocks/CU, 512 blocks = 1 full round.

union U8 { unsigned int w[4]; bf16x8 v; };

__global__ __launch_bounds__(256, 2) void k_attn(
    const unsigned short* __restrict__ qkv, const unsigned short* __restrict__ vt,
    const float* __restrict__ ct, const float* __restrict__ st,
    unsigned short* __restrict__ aout)
{
    __shared__ unsigned short smem[32768];   // 64 KB

    const int tid  = threadIdx.x;
    const int lane = tid & 63;
    const int wave = tid >> 6;               // 0..3
    const int lq   = lane & 31;
    const int hi   = lane >> 5;
    const int bh = blockIdx.y;
    const int b = bh >> 4, h = bh & 15;
    const int q0w = (blockIdx.x << 7) + (wave << 5);

    const unsigned short* Kb = qkv + (size_t)b*SEQ*QKVN + DIMS + h*HD;
    const unsigned short* Vb = vt + (size_t)bh*HD*SEQ;

    // Q fragments (B-operand: col=q=lane&31, k=hi*8+j) with in-register RoPE,
    // pre-scaled by log2e/sqrt(HD). d(ks,j) = ks*16 + hi*8 + j; pair = qf[ks+4][j].
    bf16x8 qf[8];
    {
        const float qscale = 0.08838834764831845f * 1.4426950408889634f;
        const int l = q0w + lq;
        const unsigned short* qp = qkv + (size_t)(b*SEQ + l)*QKVN + h*HD + (hi<<3);
        #pragma unroll
        for (int ks = 0; ks < 8; ++ks)
            qf[ks] = *reinterpret_cast<const bf16x8*>(qp + (ks<<4));
        #pragma unroll
        for (int ks = 0; ks < 4; ++ks){
            const int d0 = (ks<<4) + (hi<<3);
            const float4 c0 = *reinterpret_cast<const float4*>(ct + l*HD + d0);
            const float4 c1 = *reinterpret_cast<const float4*>(ct + l*HD + d0 + 4);
            const float4 s0 = *reinterpret_cast<const float4*>(st + l*HD + d0);
            const float4 s1 = *reinterpret_cast<const float4*>(st + l*HD + d0 + 4);
            const float4 C0 = *reinterpret_cast<const float4*>(ct + l*HD + d0 + 64);
            const float4 C1 = *reinterpret_cast<const float4*>(ct + l*HD + d0 + 68);
            const float4 S0 = *reinterpret_cast<const float4*>(st + l*HD + d0 + 64);
            const float4 S1 = *reinterpret_cast<const float4*>(st + l*HD + d0 + 68);
            const float cl[8] = {c0.x,c0.y,c0.z,c0.w, c1.x,c1.y,c1.z,c1.w};
            const float sl[8] = {s0.x,s0.y,s0.z,s0.w, s1.x,s1.y,s1.z,s1.w};
            const float cu[8] = {C0.x,C0.y,C0.z,C0.w, C1.x,C1.y,C1.z,C1.w};
            const float su[8] = {S0.x,S0.y,S0.z,S0.w, S1.x,S1.y,S1.z,S1.w};
            #pragma unroll
            for (int j = 0; j < 8; ++j){
                const float x1 = b2f((unsigned short)qf[ks][j]);
                const float x2 = b2f((unsigned short)qf[ks+4][j]);
                qf[ks][j]   = (short)f2b((x1*cl[j] - x2*sl[j]) * qscale);
                qf[ks+4][j] = (short)f2b((x2*cu[j] + x1*su[j]) * qscale);
            }
        }
    }

    float m_run = -3e38f, l_run = 0.f;
    f32x16 oacc[4] = {};

    #define STAGE(pb, kv0) do { \
        _Pragma("unroll") \
        for (int i = 0; i < 4; ++i){ \
            const int kr = (wave<<4) + (i<<2) + (lane>>4); \
            glds16(Kb + (size_t)((kv0) + kr)*QKVN + (((lane&15) ^ (kr&7))<<3), \
                   &smem[((pb)<<13) + (((wave<<4) + (i<<2))<<7)]); \
            const int dr = (wave<<5) + (i<<3) + (lane>>3); \
            glds16(Vb + (size_t)dr*SEQ + (kv0) + (((lane&7) ^ (dr&7))<<3), \
                   &smem[16384 + ((pb)<<13) + (((wave<<5) + (i<<3))<<6)]); \
        } \
    } while(0)

    int buf = 0;
    STAGE(0, 0);
    __syncthreads();

    for (int t = 0; t < SEQ/64; ++t){
        if (t < SEQ/64 - 1) STAGE(buf^1, (t+1)*64);

        const unsigned short* Kbuf = &smem[buf<<13];
        const unsigned short* Vbuf = &smem[16384 + (buf<<13)];

        // ---- S = K * Q  (S[kv][q]) ----
        f32x16 st0 = {}, st1 = {};
        __builtin_amdgcn_s_setprio(1);
        #pragma unroll
        for (int ks = 0; ks < 8; ++ks){
            const int col = (((ks<<1) + hi) ^ (lq & 7)) << 3;
            bf16x8 k0 = *reinterpret_cast<const bf16x8*>(&Kbuf[(lq<<7) + col]);
            bf16x8 k1 = *reinterpret_cast<const bf16x8*>(&Kbuf[((32+lq)<<7) + col]);
            st0 = __builtin_amdgcn_mfma_f32_32x32x16_bf16(k0, qf[ks], st0, 0, 0, 0);
            st1 = __builtin_amdgcn_mfma_f32_32x32x16_bf16(k1, qf[ks], st1, 0, 0, 0);
        }
        __builtin_amdgcn_s_setprio(0);

        // ---- online softmax (exp2 domain), per-lane column q ----
        float tmax = st0[0];
        #pragma unroll
        for (int r = 1; r < 16; ++r) tmax = fmaxf(tmax, st0[r]);
        #pragma unroll
        for (int r = 0; r < 16; ++r) tmax = fmaxf(tmax, st1[r]);
        tmax = fmaxf(tmax, __shfl_xor(tmax, 32));

        // defer-max (T13): skip rescale when max growth small (P bounded by 2^8)
        const bool defer = __all(tmax <= m_run + 8.0f);
        if (!defer){
            const float mnew = fmaxf(m_run, tmax);
            const float al = __builtin_amdgcn_exp2f(m_run - mnew);
            m_run = mnew;
            l_run *= al;
            #pragma unroll
            for (int dt = 0; dt < 4; ++dt) oacc[dt] *= al;
        }
        float tsum = 0.f;
        #pragma unroll
        for (int r = 0; r < 16; ++r){ float p = __builtin_amdgcn_exp2f(st0[r] - m_run); st0[r] = p; tsum += p; }
        #pragma unroll
        for (int r = 0; r < 16; ++r){ float p = __builtin_amdgcn_exp2f(st1[r] - m_run); st1[r] = p; tsum += p; }
        tsum += __shfl_xor(tsum, 32);
        l_run += tsum;

        // ---- P -> B-fragments via pack + permlane32_swap (T12) ----
        bf16x8 pf[4];
        #define MAKEPF(dA, dB, SV) do { \
            unsigned int a0 = pkbf(SV[0],SV[1]),  b0 = pkbf(SV[2],SV[3]); \
            unsigned int c0 = pkbf(SV[4],SV[5]),  d0 = pkbf(SV[6],SV[7]); \
            unsigned int a1 = pkbf(SV[8],SV[9]),  b1 = pkbf(SV[10],SV[11]); \
            unsigned int c1 = pkbf(SV[12],SV[13]),d1 = pkbf(SV[14],SV[15]); \
            asm("v_permlane32_swap_b32 %0, %1" : "+v"(a0), "+v"(c0)); \
            asm("v_permlane32_swap_b32 %0, %1" : "+v"(b0), "+v"(d0)); \
            asm("v_permlane32_swap_b32 %0, %1" : "+v"(a1), "+v"(c1)); \
            asm("v_permlane32_swap_b32 %0, %1" : "+v"(b1), "+v"(d1)); \
            U8 u; \
            u.w[0] = a0; u.w[1] = b0; u.w[2] = c0; u.w[3] = d0; dA = u.v; \
            u.w[0] = a1; u.w[1] = b1; u.w[2] = c1; u.w[3] = d1; dB = u.v; \
        } while(0)
        MAKEPF(pf[0], pf[1], st0);
        MAKEPF(pf[2], pf[3], st1);
        #undef MAKEPF

        // ---- O^T += V^T * P ----
        __builtin_amdgcn_s_setprio(1);
        #pragma unroll
        for (int dt = 0; dt < 4; ++dt){
            const int rowv = (dt<<5) + lq;
            #pragma unroll
            for (int f = 0; f < 4; ++f){
                const int col = (((f<<1) + hi) ^ (lq & 7)) << 3;
                bf16x8 vf = *reinterpret_cast<const bf16x8*>(&Vbuf[(rowv<<6) + col]);
                oacc[dt] = __builtin_amdgcn_mfma_f32_32x32x16_bf16(vf, pf[f], oacc[dt], 0, 0, 0);
            }
        }
        __builtin_amdgcn_s_setprio(0);

        __syncthreads();
        buf ^= 1;
    }
    #undef STAGE

    // ---- epilogue: O^T -> per-wave LDS transpose (reusing smem) -> coalesced global ----
    const float rl = 1.0f / l_run;
    unsigned short* oL = smem + wave*(32*132);
    #pragma unroll
    for (int dt = 0; dt < 4; ++dt)
        #pragma unroll
        for (int g = 0; g < 4; ++g){
            u16x4 w = { f2b(oacc[dt][g*4+0]*rl), f2b(oacc[dt][g*4+1]*rl),
                        f2b(oacc[dt][g*4+2]*rl), f2b(oacc[dt][g*4+3]*rl) };
            *reinterpret_cast<u16x4*>(&oL[lq*132 + (dt<<5) + (hi<<2) + (g<<3)]) = w;
        }
    #pragma unroll
    for (int i = 0; i < 16; ++i){
        const int q = (i<<1) + hi;
        u16x4 w = *reinterpret_cast<const u16x4*>(&oL[q*132 + (lq<<2)]);
        *reinterpret_cast<u16x4*>(&aout[(size_t)(b*SEQ + q0w + q)*DIMS + h*HD + (lq<<2)]) = w;
    }
}

// ---------------- launcher ----------------

extern "C" void kernel_launch(void* const* d_in, const int* in_sizes, int n_in,
                              void* d_out, int out_size, void* d_ws, size_t ws_size,
                              hipStream_t stream)
{
    const float* x    = (const float*)d_in[0];
    const float* rope = (const float*)d_in[1];
    const float* wq   = (const float*)d_in[2];
    const float* wk   = (const float*)d_in[3];
    const float* wv   = (const float*)d_in[4];
    const float* wo   = (const float*)d_in[5];
    const float* bo   = (const float*)d_in[6];
    float* out = (float*)d_out;

    char* ws = (char*)d_ws;
    unsigned short* x_bf   = (unsigned short*)(ws + 0);            // 16.8 MB
    unsigned short* wqkv   = (unsigned short*)(ws + 16777216);     // 25.2 MB
    unsigned short* wo_bf  = (unsigned short*)(ws + 41943040);     // 8.4 MB
    float*          cos_t  = (float*)(ws + 50331648);              // 1 MB
    float*          sin_t  = (float*)(ws + 51380224);              // 1 MB
    unsigned short* qkv    = (unsigned short*)(ws + 52428800);     // 50.3 MB
    unsigned short* vt     = (unsigned short*)(ws + 16777216);     // alias wqkv (dead after QKV GEMM)
    unsigned short* a_out  = (unsigned short*)(ws + 0);            // alias x_bf (dead after QKV GEMM)

    // 1. fused prep: x->bf16, 4 weights->bf16, cos/sin
    k_prep<<<dim3(4096, 7), 256, 0, stream>>>(x, wq, wk, wv, wo, rope,
                                              x_bf, wqkv, wqkv + 4194304, wqkv + 8388608, wo_bf,
                                              cos_t, sin_t);

    // 2. QKV projection: 128^2 tile, 32x32x16 MFMA, grid 32*48 = 1536
    k_gemm_bt<0><<<(MROWS/128)*(QKVN/128), 256, 0, stream>>>(x_bf, wqkv, qkv, nullptr, MROWS, QKVN, DIMS);

    // 3. fused K-rope (in place) + V transpose
    k_kropevt<<<4096, 256, 0, stream>>>(qkv, cos_t, sin_t, vt);

    // 4. attention (Q-rope in-register): 512 blocks = 2/CU x 256 CUs
    k_attn<<<dim3(SEQ/128, BATCH*HEADS), 256, 0, stream>>>(qkv, vt, cos_t, sin_t, a_out);

    // 5. output projection + bias
    k_gemm_bt<1><<<(MROWS/128)*(DIMS/128), 256, 0, stream>>>(a_out, wo_bf, out, bo, MROWS, DIMS, DIMS);
}

// Round 13
// 275.773 us; speedup vs baseline: 1.0521x; 1.0092x over previous
//
#include <hip/hip_runtime.h>
#include <hip/hip_bf16.h>
#include <stdint.h>

// Problem constants
#define DIMS  2048
#define HEADS 16
#define HD    128
#define BATCH 2
#define SEQ   2048
#define MROWS (BATCH*SEQ)   // 4096
#define QKVN  (3*DIMS)      // 6144

using bf16x8 = __attribute__((ext_vector_type(8))) short;
using f32x4  = __attribute__((ext_vector_type(4))) float;
using f32x16 = __attribute__((ext_vector_type(16))) float;
using u16x4  = __attribute__((ext_vector_type(4))) unsigned short;

__device__ __forceinline__ unsigned short f2b(float f){
    __hip_bfloat16 h = __float2bfloat16(f);
    return *reinterpret_cast<unsigned short*>(&h);
}
__device__ __forceinline__ float b2f(unsigned short u){
    __hip_bfloat16 h;
    *reinterpret_cast<unsigned short*>(&h) = u;
    return __bfloat162float(h);
}
__device__ __forceinline__ unsigned int pkbf(float lo, float hi){
    return (unsigned int)f2b(lo) | ((unsigned int)f2b(hi) << 16);
}

// async global->LDS, 16B per lane. LDS dest is wave-uniform base (+lane*16 implicit).
__device__ __forceinline__ void glds16(const void* g, void* l){
    __builtin_amdgcn_global_load_lds(
        (const __attribute__((address_space(1))) unsigned int*)g,
        (__attribute__((address_space(3))) unsigned int*)l, 16, 0, 0);
}

// ---------------- fused prep: x->bf16, 4x w->bf16, cos/sin table ----------------
// grid (4096, 7): y 0..3 -> weight y; y 4..5 -> x halves; y 6 -> cossin (1024 blocks active)

__global__ void k_prep(const float* __restrict__ x,
                       const float* __restrict__ w0, const float* __restrict__ w1,
                       const float* __restrict__ w2, const float* __restrict__ w3,
                       const float* __restrict__ rope,
                       unsigned short* __restrict__ x_bf,
                       unsigned short* __restrict__ d0, unsigned short* __restrict__ d1,
                       unsigned short* __restrict__ d2, unsigned short* __restrict__ d3,
                       float* __restrict__ ct, float* __restrict__ st){
    const int y = blockIdx.y;
    if (y == 6){
        const int i = blockIdx.x*blockDim.x + threadIdx.x;
        if (i >= SEQ*HD) return;
        const float v = rope[i];
        ct[i] = cosf(v);
        st[i] = sinf(v);
        return;
    }
    const float* src;
    unsigned short* dst;
    size_t off = 0;
    if      (y == 0){ src = w0; dst = d0; }
    else if (y == 1){ src = w1; dst = d1; }
    else if (y == 2){ src = w2; dst = d2; }
    else if (y == 3){ src = w3; dst = d3; }
    else            { src = x;  dst = x_bf; off = (size_t)(y - 4) * 1048576; }
    const size_t i = off + blockIdx.x*blockDim.x + threadIdx.x;
    const float4 v = reinterpret_cast<const float4*>(src)[i];
    u16x4 o = { f2b(v.x), f2b(v.y), f2b(v.z), f2b(v.w) };
    *reinterpret_cast<u16x4*>(dst + 4*i) = o;
}

// ---------------- fused K-rope + V-transpose ----------------
// grid 4096 x 256. bid < 2048: RoPE in-place on K section (bf16x8 vectorized).
// bid >= 2048: V transpose qkv[b][l][2*DIMS + h*128+d] -> vt[(b*16+h)*128+d][l].
// NOTE (R9/R10 lesson): fusing these into the GEMM epilogue regressed twice —
// LDS +1KB cost a blocks/CU step (R9), multi-region epilogue cost +32 VGPR (R10).
// The GEMM plateau depends on its lean 76-VGPR / 32KB-LDS body; keep this separate.

__global__ void k_kropevt(unsigned short* __restrict__ qkv,
                          const float* __restrict__ ct, const float* __restrict__ st,
                          unsigned short* __restrict__ vt){
    __shared__ unsigned short t[64*68];
    const int bid = blockIdx.x;
    if (bid < 2048){
        const int idx = bid*blockDim.x + threadIdx.x;   // 524288
        const int d0 = (idx & 7) << 3;
        const int h  = (idx >> 3) & (HEADS-1);
        const int l  = (idx >> 7) & (SEQ-1);
        const int b  = idx >> 18;
        const float4* cp = reinterpret_cast<const float4*>(ct + l*HD + d0);
        const float4* sp = reinterpret_cast<const float4*>(st + l*HD + d0);
        const float4 cl0 = cp[0],  cl1 = cp[1];
        const float4 sl0 = sp[0],  sl1 = sp[1];
        const float4 cu0 = cp[16], cu1 = cp[17];
        const float4 su0 = sp[16], su1 = sp[17];
        const float cl[8] = {cl0.x,cl0.y,cl0.z,cl0.w, cl1.x,cl1.y,cl1.z,cl1.w};
        const float sl[8] = {sl0.x,sl0.y,sl0.z,sl0.w, sl1.x,sl1.y,sl1.z,sl1.w};
        const float cu[8] = {cu0.x,cu0.y,cu0.z,cu0.w, cu1.x,cu1.y,cu1.z,cu1.w};
        const float su[8] = {su0.x,su0.y,su0.z,su0.w, su1.x,su1.y,su1.z,su1.w};
        unsigned short* rp = qkv + (size_t)(b*SEQ + l)*QKVN + DIMS + h*HD + d0;  // K section
        bf16x8 lo = *reinterpret_cast<const bf16x8*>(rp);
        bf16x8 hi = *reinterpret_cast<const bf16x8*>(rp + 64);
        bf16x8 olo, ohi;
        #pragma unroll
        for (int j = 0; j < 8; ++j){
            const float x1 = b2f((unsigned short)lo[j]);
            const float x2 = b2f((unsigned short)hi[j]);
            olo[j] = (short)f2b(x1*cl[j] - x2*sl[j]);
            ohi[j] = (short)f2b(x2*cu[j] + x1*su[j]);
        }
        *reinterpret_cast<bf16x8*>(rp)      = olo;
        *reinterpret_cast<bf16x8*>(rp + 64) = ohi;
        return;
    }
    // ---- V transpose ----
    const int bid2 = bid - 2048;
    const int lt = bid2 & 31;
    const int dt = (bid2 >> 5) & 1;
    const int bh = bid2 >> 6;
    const int b = bh >> 4, h = bh & 15;
    const int tid = threadIdx.x;
    const int l0 = lt << 6;
    #pragma unroll
    for (int it = 0; it < 4; ++it){
        const int c = tid + (it<<8);
        const int l = c >> 4;
        const int d4 = (c & 15) << 2;
        const u16x4 v = *reinterpret_cast<const u16x4*>(
            qkv + (size_t)(b*SEQ + l0 + l)*QKVN + 2*DIMS + h*HD + (dt<<6) + d4);
        *reinterpret_cast<u16x4*>(&t[l*68 + d4]) = v;
    }
    __syncthreads();
    #pragma unroll
    for (int it = 0; it < 4; ++it){
        const int c = tid + (it<<8);
        const int d = c >> 4;
        const int l4 = (c & 15) << 2;
        u16x4 o = { t[(l4+0)*68 + d], t[(l4+1)*68 + d], t[(l4+2)*68 + d], t[(l4+3)*68 + d] };
        *reinterpret_cast<u16x4*>(&vt[((size_t)bh*HD + (dt<<6) + d)*SEQ + l0 + l4]) = o;
    }
}

// ---------------- 128x128 GEMM (m97 staging) with 32x32x16 MFMA ----------------
// R12 winner: mfma_f32_32x32x16_bf16 (half the MFMA instruction count; VALUBusy 47->16).
// Known artifact: ~12.6M LDS bank conflicts from the 32-row fragment-read shape —
// unmodellable pass-grouping, net still faster than the 16x16 shape. Do not touch.

template<int FINAL>
__global__ __launch_bounds__(256) void k_gemm_bt(
    const unsigned short* __restrict__ A, const unsigned short* __restrict__ B,
    void* __restrict__ C, const float* __restrict__ bias, int M, int N, int K)
{
    __shared__ unsigned short lA[128*64];
    __shared__ unsigned short lB[128*64];
    const int tid  = threadIdx.x;
    const int lane = tid & 63;
    const int wave = tid >> 6;
    const int lq   = lane & 31;
    const int hi   = lane >> 5;

    const int nbx = N >> 7;
    const int nwg = gridDim.x;
    const int cpx = nwg >> 3;
    const int bid = blockIdx.x;
    const int wg  = (bid & 7)*cpx + (bid >> 3);
    const int m0 = (wg / nbx) << 7;
    const int n0 = (wg % nbx) << 7;

    const int wr = (wave >> 1) << 6;
    const int wc = (wave & 1) << 6;

    f32x16 acc[2][2] = {};

    const int srow_base = (wave<<3) + (lane>>3);
    const int schunk = lane & 7;

    for (int k0 = 0; k0 < K; k0 += 64){
        #pragma unroll
        for (int i = 0; i < 4; ++i){
            const int row  = (i<<5) + srow_base;
            const int scol = k0 + ((schunk ^ (row & 7)) << 3);
            glds16(A + (size_t)(m0 + row)*K + scol, &lA[((i<<5) + (wave<<3)) << 6]);
            glds16(B + (size_t)(n0 + row)*K + scol, &lB[((i<<5) + (wave<<3)) << 6]);
        }
        __syncthreads();
        #pragma unroll
        for (int ks = 0; ks < 4; ++ks){
            const int c8 = (ks<<1) + hi;
            bf16x8 af[2], bfr[2];
            #pragma unroll
            for (int ti = 0; ti < 2; ++ti){
                const int rowa = wr + (ti<<5) + lq;
                af[ti] = *reinterpret_cast<const bf16x8*>(&lA[(rowa<<6) + ((c8 ^ (rowa&7))<<3)]);
            }
            #pragma unroll
            for (int tj = 0; tj < 2; ++tj){
                const int rowb = wc + (tj<<5) + lq;
                bfr[tj] = *reinterpret_cast<const bf16x8*>(&lB[(rowb<<6) + ((c8 ^ (rowb&7))<<3)]);
            }
            #pragma unroll
            for (int ti = 0; ti < 2; ++ti)
                #pragma unroll
                for (int tj = 0; tj < 2; ++tj)
                    acc[ti][tj] = __builtin_amdgcn_mfma_f32_32x32x16_bf16(af[ti], bfr[tj], acc[ti][tj], 0, 0, 0);
        }
        __syncthreads();
    }

    // epilogue: D layout (32x32): col=lane&31, row=(r&3)+8*(r>>2)+4*(lane>>5)
    #pragma unroll
    for (int ti = 0; ti < 2; ++ti)
        #pragma unroll
        for (int tj = 0; tj < 2; ++tj)
            #pragma unroll
            for (int r = 0; r < 16; ++r){
                const int row = (r&3) + ((r>>2)<<3) + (hi<<2);
                const int gm = m0 + wr + (ti<<5) + row;
                const int gn = n0 + wc + (tj<<5) + lq;
                const float v = acc[ti][tj][r];
                if (FINAL)
                    reinterpret_cast<float*>(C)[(size_t)gm*N + gn] = v + bias[gn];
                else
                    reinterpret_cast<unsigned short*>(C)[(size_t)gm*N + gn] = f2b(v);
            }
}

// ---------------- flash attention, swapped-operand 32x32, 8-wave blocks ----------------
// R13 change: QBLK 128->256 (8 waves x 32 q-rows, 512 threads), grid (SEQ/256=8, 32)
// = 256 blocks = 1/CU. Waves/CU unchanged (8 = 2/SIMD) but per-CU K/V staging bytes,
// glds16 count, and L2/L3 re-read traffic HALVE (8 q-blocks re-read K/V instead of 16).
// Per-wave compute identical to R12. Epilogue is two-phase (lO fits 4 waves at a time).

union U8 { unsigned int w[4]; bf16x8 v; };

__global__ __launch_bounds__(512, 2) void k_attn(
    const unsigned short* __restrict__ qkv, const unsigned short* __restrict__ vt,
    const float* __restrict__ ct, const float* __restrict__ st,
    unsigned short* __restrict__ aout)
{
    __shared__ unsigned short smem[32768];   // 64 KB: lK dbuf [pb<<13], lV dbuf 16384+[pb<<13]

    const int tid  = threadIdx.x;
    const int lane = tid & 63;
    const int wave = tid >> 6;               // 0..7
    const int lq   = lane & 31;
    const int hi   = lane >> 5;
    const int bh = blockIdx.y;
    const int b = bh >> 4, h = bh & 15;
    const int q0w = (blockIdx.x << 8) + (wave << 5);

    const unsigned short* Kb = qkv + (size_t)b*SEQ*QKVN + DIMS + h*HD;
    const unsigned short* Vb = vt + (size_t)bh*HD*SEQ;

    // Q fragments (B-operand: col=q=lane&31, k=hi*8+j) with in-register RoPE,
    // pre-scaled by log2e/sqrt(HD). d(ks,j) = ks*16 + hi*8 + j; pair = qf[ks+4][j].
    bf16x8 qf[8];
    {
        const float qscale = 0.08838834764831845f * 1.4426950408889634f;
        const int l = q0w + lq;
        const unsigned short* qp = qkv + (size_t)(b*SEQ + l)*QKVN + h*HD + (hi<<3);
        #pragma unroll
        for (int ks = 0; ks < 8; ++ks)
            qf[ks] = *reinterpret_cast<const bf16x8*>(qp + (ks<<4));
        #pragma unroll
        for (int ks = 0; ks < 4; ++ks){
            const int d0 = (ks<<4) + (hi<<3);
            const float4 c0 = *reinterpret_cast<const float4*>(ct + l*HD + d0);
            const float4 c1 = *reinterpret_cast<const float4*>(ct + l*HD + d0 + 4);
            const float4 s0 = *reinterpret_cast<const float4*>(st + l*HD + d0);
            const float4 s1 = *reinterpret_cast<const float4*>(st + l*HD + d0 + 4);
            const float4 C0 = *reinterpret_cast<const float4*>(ct + l*HD + d0 + 64);
            const float4 C1 = *reinterpret_cast<const float4*>(ct + l*HD + d0 + 68);
            const float4 S0 = *reinterpret_cast<const float4*>(st + l*HD + d0 + 64);
            const float4 S1 = *reinterpret_cast<const float4*>(st + l*HD + d0 + 68);
            const float cl[8] = {c0.x,c0.y,c0.z,c0.w, c1.x,c1.y,c1.z,c1.w};
            const float sl[8] = {s0.x,s0.y,s0.z,s0.w, s1.x,s1.y,s1.z,s1.w};
            const float cu[8] = {C0.x,C0.y,C0.z,C0.w, C1.x,C1.y,C1.z,C1.w};
            const float su[8] = {S0.x,S0.y,S0.z,S0.w, S1.x,S1.y,S1.z,S1.w};
            #pragma unroll
            for (int j = 0; j < 8; ++j){
                const float x1 = b2f((unsigned short)qf[ks][j]);
                const float x2 = b2f((unsigned short)qf[ks+4][j]);
                qf[ks][j]   = (short)f2b((x1*cl[j] - x2*sl[j]) * qscale);
                qf[ks+4][j] = (short)f2b((x2*cu[j] + x1*su[j]) * qscale);
            }
        }
    }

    float m_run = -3e38f, l_run = 0.f;
    f32x16 oacc[4] = {};

    // 8-wave staging: per wave 2 K-calls (4 rows each) + 2 V-calls (8 rows each)
    #define STAGE(pb, kv0) do { \
        _Pragma("unroll") \
        for (int i = 0; i < 2; ++i){ \
            const int kr = (wave<<3) + (i<<2) + (lane>>4); \
            glds16(Kb + (size_t)((kv0) + kr)*QKVN + (((lane&15) ^ (kr&7))<<3), \
                   &smem[((pb)<<13) + (((wave<<3) + (i<<2))<<7)]); \
            const int dr = (wave<<4) + (i<<3) + (lane>>3); \
            glds16(Vb + (size_t)dr*SEQ + (kv0) + (((lane&7) ^ (dr&7))<<3), \
                   &smem[16384 + ((pb)<<13) + (((wave<<4) + (i<<3))<<6)]); \
        } \
    } while(0)

    int buf = 0;
    STAGE(0, 0);
    __syncthreads();

    for (int t = 0; t < SEQ/64; ++t){
        if (t < SEQ/64 - 1) STAGE(buf^1, (t+1)*64);

        const unsigned short* Kbuf = &smem[buf<<13];
        const unsigned short* Vbuf = &smem[16384 + (buf<<13)];

        // ---- S = K * Q  (S[kv][q]) ----
        f32x16 st0 = {}, st1 = {};
        __builtin_amdgcn_s_setprio(1);
        #pragma unroll
        for (int ks = 0; ks < 8; ++ks){
            const int col = (((ks<<1) + hi) ^ (lq & 7)) << 3;
            bf16x8 k0 = *reinterpret_cast<const bf16x8*>(&Kbuf[(lq<<7) + col]);
            bf16x8 k1 = *reinterpret_cast<const bf16x8*>(&Kbuf[((32+lq)<<7) + col]);
            st0 = __builtin_amdgcn_mfma_f32_32x32x16_bf16(k0, qf[ks], st0, 0, 0, 0);
            st1 = __builtin_amdgcn_mfma_f32_32x32x16_bf16(k1, qf[ks], st1, 0, 0, 0);
        }
        __builtin_amdgcn_s_setprio(0);

        // ---- online softmax (exp2 domain), per-lane column q ----
        float tmax = st0[0];
        #pragma unroll
        for (int r = 1; r < 16; ++r) tmax = fmaxf(tmax, st0[r]);
        #pragma unroll
        for (int r = 0; r < 16; ++r) tmax = fmaxf(tmax, st1[r]);
        tmax = fmaxf(tmax, __shfl_xor(tmax, 32));

        // defer-max (T13): skip rescale when max growth small (P bounded by 2^8)
        const bool defer = __all(tmax <= m_run + 8.0f);
        if (!defer){
            const float mnew = fmaxf(m_run, tmax);
            const float al = __builtin_amdgcn_exp2f(m_run - mnew);
            m_run = mnew;
            l_run *= al;
            #pragma unroll
            for (int dt = 0; dt < 4; ++dt) oacc[dt] *= al;
        }
        float tsum = 0.f;
        #pragma unroll
        for (int r = 0; r < 16; ++r){ float p = __builtin_amdgcn_exp2f(st0[r] - m_run); st0[r] = p; tsum += p; }
        #pragma unroll
        for (int r = 0; r < 16; ++r){ float p = __builtin_amdgcn_exp2f(st1[r] - m_run); st1[r] = p; tsum += p; }
        tsum += __shfl_xor(tsum, 32);
        l_run += tsum;

        // ---- P -> B-fragments via pack + permlane32_swap (T12) ----
        bf16x8 pf[4];
        #define MAKEPF(dA, dB, SV) do { \
            unsigned int a0 = pkbf(SV[0],SV[1]),  b0 = pkbf(SV[2],SV[3]); \
            unsigned int c0 = pkbf(SV[4],SV[5]),  d0 = pkbf(SV[6],SV[7]); \
            unsigned int a1 = pkbf(SV[8],SV[9]),  b1 = pkbf(SV[10],SV[11]); \
            unsigned int c1 = pkbf(SV[12],SV[13]),d1 = pkbf(SV[14],SV[15]); \
            asm("v_permlane32_swap_b32 %0, %1" : "+v"(a0), "+v"(c0)); \
            asm("v_permlane32_swap_b32 %0, %1" : "+v"(b0), "+v"(d0)); \
            asm("v_permlane32_swap_b32 %0, %1" : "+v"(a1), "+v"(c1)); \
            asm("v_permlane32_swap_b32 %0, %1" : "+v"(b1), "+v"(d1)); \
            U8 u; \
            u.w[0] = a0; u.w[1] = b0; u.w[2] = c0; u.w[3] = d0; dA = u.v; \
            u.w[0] = a1; u.w[1] = b1; u.w[2] = c1; u.w[3] = d1; dB = u.v; \
        } while(0)
        MAKEPF(pf[0], pf[1], st0);
        MAKEPF(pf[2], pf[3], st1);
        #undef MAKEPF

        // ---- O^T += V^T * P ----
        __builtin_amdgcn_s_setprio(1);
        #pragma unroll
        for (int dt = 0; dt < 4; ++dt){
            const int rowv = (dt<<5) + lq;
            #pragma unroll
            for (int f = 0; f < 4; ++f){
                const int col = (((f<<1) + hi) ^ (lq & 7)) << 3;
                bf16x8 vf = *reinterpret_cast<const bf16x8*>(&Vbuf[(rowv<<6) + col]);
                oacc[dt] = __builtin_amdgcn_mfma_f32_32x32x16_bf16(vf, pf[f], oacc[dt], 0, 0, 0);
            }
        }
        __builtin_amdgcn_s_setprio(0);

        __syncthreads();
        buf ^= 1;
    }
    #undef STAGE

    // ---- epilogue: two-phase O^T -> LDS transpose (4 waves per phase) -> global ----
    const float rl = 1.0f / l_run;
    #pragma unroll
    for (int ph = 0; ph < 2; ++ph){
        if ((wave >> 2) == ph){
            unsigned short* oL = smem + (wave & 3)*(32*132);
            #pragma unroll
            for (int dt = 0; dt < 4; ++dt)
                #pragma unroll
                for (int g = 0; g < 4; ++g){
                    u16x4 w = { f2b(oacc[dt][g*4+0]*rl), f2b(oacc[dt][g*4+1]*rl),
                                f2b(oacc[dt][g*4+2]*rl), f2b(oacc[dt][g*4+3]*rl) };
                    *reinterpret_cast<u16x4*>(&oL[lq*132 + (dt<<5) + (hi<<2) + (g<<3)]) = w;
                }
        }
        __syncthreads();
        if ((wave >> 2) == ph){
            const unsigned short* oL = smem + (wave & 3)*(32*132);
            #pragma unroll
            for (int i = 0; i < 16; ++i){
                const int q = (i<<1) + hi;
                u16x4 w = *reinterpret_cast<const u16x4*>(&oL[q*132 + (lq<<2)]);
                *reinterpret_cast<u16x4*>(&aout[(size_t)(b*SEQ + q0w + q)*DIMS + h*HD + (lq<<2)]) = w;
            }
        }
        __syncthreads();
    }
}

// ---------------- launcher ----------------

extern "C" void kernel_launch(void* const* d_in, const int* in_sizes, int n_in,
                              void* d_out, int out_size, void* d_ws, size_t ws_size,
                              hipStream_t stream)
{
    const float* x    = (const float*)d_in[0];
    const float* rope = (const float*)d_in[1];
    const float* wq   = (const float*)d_in[2];
    const float* wk   = (const float*)d_in[3];
    const float* wv   = (const float*)d_in[4];
    const float* wo   = (const float*)d_in[5];
    const float* bo   = (const float*)d_in[6];
    float* out = (float*)d_out;

    char* ws = (char*)d_ws;
    unsigned short* x_bf   = (unsigned short*)(ws + 0);            // 16.8 MB
    unsigned short* wqkv   = (unsigned short*)(ws + 16777216);     // 25.2 MB
    unsigned short* wo_bf  = (unsigned short*)(ws + 41943040);     // 8.4 MB
    float*          cos_t  = (float*)(ws + 50331648);              // 1 MB
    float*          sin_t  = (float*)(ws + 51380224);              // 1 MB
    unsigned short* qkv    = (unsigned short*)(ws + 52428800);     // 50.3 MB
    unsigned short* vt     = (unsigned short*)(ws + 16777216);     // alias wqkv (dead after QKV GEMM)
    unsigned short* a_out  = (unsigned short*)(ws + 0);            // alias x_bf (dead after QKV GEMM)

    // 1. fused prep: x->bf16, 4 weights->bf16, cos/sin
    k_prep<<<dim3(4096, 7), 256, 0, stream>>>(x, wq, wk, wv, wo, rope,
                                              x_bf, wqkv, wqkv + 4194304, wqkv + 8388608, wo_bf,
                                              cos_t, sin_t);

    // 2. QKV projection: 128^2 tile, 32x32x16 MFMA, grid 32*48 = 1536
    k_gemm_bt<0><<<(MROWS/128)*(QKVN/128), 256, 0, stream>>>(x_bf, wqkv, qkv, nullptr, MROWS, QKVN, DIMS);

    // 3. fused K-rope (in place) + V transpose
    k_kropevt<<<4096, 256, 0, stream>>>(qkv, cos_t, sin_t, vt);

    // 4. attention (Q-rope in-register): QBLK=256, 256 blocks = 1/CU, 8 waves
    k_attn<<<dim3(SEQ/256, BATCH*HEADS), 512, 0, stream>>>(qkv, vt, cos_t, sin_t, a_out);

    // 5. output projection + bias
    k_gemm_bt<1><<<(MROWS/128)*(DIMS/128), 256, 0, stream>>>(a_out, wo_bf, out, bo, MROWS, DIMS, DIMS);
}

// Round 14
// 273.649 us; speedup vs baseline: 1.0602x; 1.0078x over previous
//
#include <hip/hip_runtime.h>
#include <hip/hip_bf16.h>
#include <stdint.h>

// Problem constants
#define DIMS  2048
#define HEADS 16
#define HD    128
#define BATCH 2
#define SEQ   2048
#define MROWS (BATCH*SEQ)   // 4096
#define QKVN  (3*DIMS)      // 6144

using bf16x8 = __attribute__((ext_vector_type(8))) short;
using f32x4  = __attribute__((ext_vector_type(4))) float;
using f32x16 = __attribute__((ext_vector_type(16))) float;
using u16x4  = __attribute__((ext_vector_type(4))) unsigned short;

__device__ __forceinline__ unsigned short f2b(float f){
    __hip_bfloat16 h = __float2bfloat16(f);
    return *reinterpret_cast<unsigned short*>(&h);
}
__device__ __forceinline__ float b2f(unsigned short u){
    __hip_bfloat16 h;
    *reinterpret_cast<unsigned short*>(&h) = u;
    return __bfloat162float(h);
}
__device__ __forceinline__ unsigned int pkbf(float lo, float hi){
    return (unsigned int)f2b(lo) | ((unsigned int)f2b(hi) << 16);
}

// async global->LDS, 16B per lane. LDS dest is wave-uniform base (+lane*16 implicit).
__device__ __forceinline__ void glds16(const void* g, void* l){
    __builtin_amdgcn_global_load_lds(
        (const __attribute__((address_space(1))) unsigned int*)g,
        (__attribute__((address_space(3))) unsigned int*)l, 16, 0, 0);
}

// ---------------- fused prep: x->bf16, 4x w->bf16, cos/sin table ----------------
// grid (4096, 7): y 0..3 -> weight y; y 4..5 -> x halves; y 6 -> cossin (1024 blocks active)

__global__ void k_prep(const float* __restrict__ x,
                       const float* __restrict__ w0, const float* __restrict__ w1,
                       const float* __restrict__ w2, const float* __restrict__ w3,
                       const float* __restrict__ rope,
                       unsigned short* __restrict__ x_bf,
                       unsigned short* __restrict__ d0, unsigned short* __restrict__ d1,
                       unsigned short* __restrict__ d2, unsigned short* __restrict__ d3,
                       float* __restrict__ ct, float* __restrict__ st){
    const int y = blockIdx.y;
    if (y == 6){
        const int i = blockIdx.x*blockDim.x + threadIdx.x;
        if (i >= SEQ*HD) return;
        const float v = rope[i];
        ct[i] = cosf(v);
        st[i] = sinf(v);
        return;
    }
    const float* src;
    unsigned short* dst;
    size_t off = 0;
    if      (y == 0){ src = w0; dst = d0; }
    else if (y == 1){ src = w1; dst = d1; }
    else if (y == 2){ src = w2; dst = d2; }
    else if (y == 3){ src = w3; dst = d3; }
    else            { src = x;  dst = x_bf; off = (size_t)(y - 4) * 1048576; }
    const size_t i = off + blockIdx.x*blockDim.x + threadIdx.x;
    const float4 v = reinterpret_cast<const float4*>(src)[i];
    u16x4 o = { f2b(v.x), f2b(v.y), f2b(v.z), f2b(v.w) };
    *reinterpret_cast<u16x4*>(dst + 4*i) = o;
}

// ---------------- fused K-rope + V-transpose ----------------
// grid 4096 x 256. bid < 2048: RoPE in-place on K section (bf16x8 vectorized).
// bid >= 2048: V transpose qkv[b][l][2*DIMS + h*128+d] -> vt[(b*16+h)*128+d][l].
// NOTE (R9/R10 lesson): fusing these into the GEMM epilogue regressed twice —
// LDS +1KB cost a blocks/CU step (R9), multi-region epilogue cost +32 VGPR (R10).
// The GEMM plateau depends on its lean 76-VGPR / 32KB-LDS body; keep this separate.

__global__ void k_kropevt(unsigned short* __restrict__ qkv,
                          const float* __restrict__ ct, const float* __restrict__ st,
                          unsigned short* __restrict__ vt){
    __shared__ unsigned short t[64*68];
    const int bid = blockIdx.x;
    if (bid < 2048){
        const int idx = bid*blockDim.x + threadIdx.x;   // 524288
        const int d0 = (idx & 7) << 3;
        const int h  = (idx >> 3) & (HEADS-1);
        const int l  = (idx >> 7) & (SEQ-1);
        const int b  = idx >> 18;
        const float4* cp = reinterpret_cast<const float4*>(ct + l*HD + d0);
        const float4* sp = reinterpret_cast<const float4*>(st + l*HD + d0);
        const float4 cl0 = cp[0],  cl1 = cp[1];
        const float4 sl0 = sp[0],  sl1 = sp[1];
        const float4 cu0 = cp[16], cu1 = cp[17];
        const float4 su0 = sp[16], su1 = sp[17];
        const float cl[8] = {cl0.x,cl0.y,cl0.z,cl0.w, cl1.x,cl1.y,cl1.z,cl1.w};
        const float sl[8] = {sl0.x,sl0.y,sl0.z,sl0.w, sl1.x,sl1.y,sl1.z,sl1.w};
        const float cu[8] = {cu0.x,cu0.y,cu0.z,cu0.w, cu1.x,cu1.y,cu1.z,cu1.w};
        const float su[8] = {su0.x,su0.y,su0.z,su0.w, su1.x,su1.y,su1.z,su1.w};
        unsigned short* rp = qkv + (size_t)(b*SEQ + l)*QKVN + DIMS + h*HD + d0;  // K section
        bf16x8 lo = *reinterpret_cast<const bf16x8*>(rp);
        bf16x8 hi = *reinterpret_cast<const bf16x8*>(rp + 64);
        bf16x8 olo, ohi;
        #pragma unroll
        for (int j = 0; j < 8; ++j){
            const float x1 = b2f((unsigned short)lo[j]);
            const float x2 = b2f((unsigned short)hi[j]);
            olo[j] = (short)f2b(x1*cl[j] - x2*sl[j]);
            ohi[j] = (short)f2b(x2*cu[j] + x1*su[j]);
        }
        *reinterpret_cast<bf16x8*>(rp)      = olo;
        *reinterpret_cast<bf16x8*>(rp + 64) = ohi;
        return;
    }
    // ---- V transpose ----
    const int bid2 = bid - 2048;
    const int lt = bid2 & 31;
    const int dt = (bid2 >> 5) & 1;
    const int bh = bid2 >> 6;
    const int b = bh >> 4, h = bh & 15;
    const int tid = threadIdx.x;
    const int l0 = lt << 6;
    #pragma unroll
    for (int it = 0; it < 4; ++it){
        const int c = tid + (it<<8);
        const int l = c >> 4;
        const int d4 = (c & 15) << 2;
        const u16x4 v = *reinterpret_cast<const u16x4*>(
            qkv + (size_t)(b*SEQ + l0 + l)*QKVN + 2*DIMS + h*HD + (dt<<6) + d4);
        *reinterpret_cast<u16x4*>(&t[l*68 + d4]) = v;
    }
    __syncthreads();
    #pragma unroll
    for (int it = 0; it < 4; ++it){
        const int c = tid + (it<<8);
        const int d = c >> 4;
        const int l4 = (c & 15) << 2;
        u16x4 o = { t[(l4+0)*68 + d], t[(l4+1)*68 + d], t[(l4+2)*68 + d], t[(l4+3)*68 + d] };
        *reinterpret_cast<u16x4*>(&vt[((size_t)bh*HD + (dt<<6) + d)*SEQ + l0 + l4]) = o;
    }
}

// ---------------- 128x128 GEMM (m97 staging) with 32x32x16 MFMA ----------------
// R12 winner: mfma_f32_32x32x16_bf16 (half the MFMA instruction count; VALUBusy 47->16).
// Known artifact: ~12.6M LDS bank conflicts from the 32-row fragment-read shape —
// net still faster than the 16x16 shape. Do not touch.

template<int FINAL>
__global__ __launch_bounds__(256) void k_gemm_bt(
    const unsigned short* __restrict__ A, const unsigned short* __restrict__ B,
    void* __restrict__ C, const float* __restrict__ bias, int M, int N, int K)
{
    __shared__ unsigned short lA[128*64];
    __shared__ unsigned short lB[128*64];
    const int tid  = threadIdx.x;
    const int lane = tid & 63;
    const int wave = tid >> 6;
    const int lq   = lane & 31;
    const int hi   = lane >> 5;

    const int nbx = N >> 7;
    const int nwg = gridDim.x;
    const int cpx = nwg >> 3;
    const int bid = blockIdx.x;
    const int wg  = (bid & 7)*cpx + (bid >> 3);
    const int m0 = (wg / nbx) << 7;
    const int n0 = (wg % nbx) << 7;

    const int wr = (wave >> 1) << 6;
    const int wc = (wave & 1) << 6;

    f32x16 acc[2][2] = {};

    const int srow_base = (wave<<3) + (lane>>3);
    const int schunk = lane & 7;

    for (int k0 = 0; k0 < K; k0 += 64){
        #pragma unroll
        for (int i = 0; i < 4; ++i){
            const int row  = (i<<5) + srow_base;
            const int scol = k0 + ((schunk ^ (row & 7)) << 3);
            glds16(A + (size_t)(m0 + row)*K + scol, &lA[((i<<5) + (wave<<3)) << 6]);
            glds16(B + (size_t)(n0 + row)*K + scol, &lB[((i<<5) + (wave<<3)) << 6]);
        }
        __syncthreads();
        #pragma unroll
        for (int ks = 0; ks < 4; ++ks){
            const int c8 = (ks<<1) + hi;
            bf16x8 af[2], bfr[2];
            #pragma unroll
            for (int ti = 0; ti < 2; ++ti){
                const int rowa = wr + (ti<<5) + lq;
                af[ti] = *reinterpret_cast<const bf16x8*>(&lA[(rowa<<6) + ((c8 ^ (rowa&7))<<3)]);
            }
            #pragma unroll
            for (int tj = 0; tj < 2; ++tj){
                const int rowb = wc + (tj<<5) + lq;
                bfr[tj] = *reinterpret_cast<const bf16x8*>(&lB[(rowb<<6) + ((c8 ^ (rowb&7))<<3)]);
            }
            #pragma unroll
            for (int ti = 0; ti < 2; ++ti)
                #pragma unroll
                for (int tj = 0; tj < 2; ++tj)
                    acc[ti][tj] = __builtin_amdgcn_mfma_f32_32x32x16_bf16(af[ti], bfr[tj], acc[ti][tj], 0, 0, 0);
        }
        __syncthreads();
    }

    // epilogue: D layout (32x32): col=lane&31, row=(r&3)+8*(r>>2)+4*(lane>>5)
    #pragma unroll
    for (int ti = 0; ti < 2; ++ti)
        #pragma unroll
        for (int tj = 0; tj < 2; ++tj)
            #pragma unroll
            for (int r = 0; r < 16; ++r){
                const int row = (r&3) + ((r>>2)<<3) + (hi<<2);
                const int gm = m0 + wr + (ti<<5) + row;
                const int gn = n0 + wc + (tj<<5) + lq;
                const float v = acc[ti][tj][r];
                if (FINAL)
                    reinterpret_cast<float*>(C)[(size_t)gm*N + gn] = v + bias[gn];
                else
                    reinterpret_cast<unsigned short*>(C)[(size_t)gm*N + gn] = f2b(v);
            }
}

// ---------------- flash attention, swapped-operand 32x32, 8-wave, KVBLK=128 ----------------
// R14 change: KV tile 64 -> 128. Halves iteration count (32->16): half the barrier/drain
// events, 2x MFMA per phase. LDS 128KB (K[2][128][128] + V[2][128][128]) at 1 block/CU;
// occupancy unchanged (8 waves = 2/SIMD). st[4] accumulators; pf[8]; VGPR ~220 < 256.
// Tile pitch now 128 elems (16 chunks of 8); swizzle chunk ^= (row&7) unchanged.

union U8 { unsigned int w[4]; bf16x8 v; };

#define VOFF 32768   // V region offset in smem (elems)

__global__ __launch_bounds__(512, 2) void k_attn(
    const unsigned short* __restrict__ qkv, const unsigned short* __restrict__ vt,
    const float* __restrict__ ct, const float* __restrict__ st,
    unsigned short* __restrict__ aout)
{
    __shared__ unsigned short smem[65536];   // 128 KB

    const int tid  = threadIdx.x;
    const int lane = tid & 63;
    const int wave = tid >> 6;               // 0..7
    const int lq   = lane & 31;
    const int hi   = lane >> 5;
    const int bh = blockIdx.y;
    const int b = bh >> 4, h = bh & 15;
    const int q0w = (blockIdx.x << 8) + (wave << 5);

    const unsigned short* Kb = qkv + (size_t)b*SEQ*QKVN + DIMS + h*HD;
    const unsigned short* Vb = vt + (size_t)bh*HD*SEQ;

    // Q fragments (B-operand: col=q=lane&31, k=hi*8+j) with in-register RoPE,
    // pre-scaled by log2e/sqrt(HD). d(ks,j) = ks*16 + hi*8 + j; pair = qf[ks+4][j].
    bf16x8 qf[8];
    {
        const float qscale = 0.08838834764831845f * 1.4426950408889634f;
        const int l = q0w + lq;
        const unsigned short* qp = qkv + (size_t)(b*SEQ + l)*QKVN + h*HD + (hi<<3);
        #pragma unroll
        for (int ks = 0; ks < 8; ++ks)
            qf[ks] = *reinterpret_cast<const bf16x8*>(qp + (ks<<4));
        #pragma unroll
        for (int ks = 0; ks < 4; ++ks){
            const int d0 = (ks<<4) + (hi<<3);
            const float4 c0 = *reinterpret_cast<const float4*>(ct + l*HD + d0);
            const float4 c1 = *reinterpret_cast<const float4*>(ct + l*HD + d0 + 4);
            const float4 s0 = *reinterpret_cast<const float4*>(st + l*HD + d0);
            const float4 s1 = *reinterpret_cast<const float4*>(st + l*HD + d0 + 4);
            const float4 C0 = *reinterpret_cast<const float4*>(ct + l*HD + d0 + 64);
            const float4 C1 = *reinterpret_cast<const float4*>(ct + l*HD + d0 + 68);
            const float4 S0 = *reinterpret_cast<const float4*>(st + l*HD + d0 + 64);
            const float4 S1 = *reinterpret_cast<const float4*>(st + l*HD + d0 + 68);
            const float cl[8] = {c0.x,c0.y,c0.z,c0.w, c1.x,c1.y,c1.z,c1.w};
            const float sl[8] = {s0.x,s0.y,s0.z,s0.w, s1.x,s1.y,s1.z,s1.w};
            const float cu[8] = {C0.x,C0.y,C0.z,C0.w, C1.x,C1.y,C1.z,C1.w};
            const float su[8] = {S0.x,S0.y,S0.z,S0.w, S1.x,S1.y,S1.z,S1.w};
            #pragma unroll
            for (int j = 0; j < 8; ++j){
                const float x1 = b2f((unsigned short)qf[ks][j]);
                const float x2 = b2f((unsigned short)qf[ks+4][j]);
                qf[ks][j]   = (short)f2b((x1*cl[j] - x2*sl[j]) * qscale);
                qf[ks+4][j] = (short)f2b((x2*cu[j] + x1*su[j]) * qscale);
            }
        }
    }

    float m_run = -3e38f, l_run = 0.f;
    f32x16 oacc[4] = {};

    // staging: per wave 4 K-calls (4 kv-rows each) + 4 V-calls (4 d-rows each); pitch 128.
    #define STAGE(pb, kv0) do { \
        _Pragma("unroll") \
        for (int i = 0; i < 4; ++i){ \
            const int kr = (wave<<4) + (i<<2) + (lane>>4); \
            glds16(Kb + (size_t)((kv0) + kr)*QKVN + ((((lane&15) ^ (kr&7)))<<3), \
                   &smem[((pb)<<14) + (((wave<<4) + (i<<2))<<7)]); \
            const int dr = (wave<<4) + (i<<2) + (lane>>4); \
            glds16(Vb + (size_t)dr*SEQ + (kv0) + ((((lane&15) ^ (dr&7)))<<3), \
                   &smem[VOFF + ((pb)<<14) + (((wave<<4) + (i<<2))<<7)]); \
        } \
    } while(0)

    int buf = 0;
    STAGE(0, 0);
    __syncthreads();

    for (int t = 0; t < SEQ/128; ++t){
        if (t < SEQ/128 - 1) STAGE(buf^1, (t+1)*128);

        const unsigned short* Kbuf = &smem[buf<<14];
        const unsigned short* Vbuf = &smem[VOFF + (buf<<14)];

        // ---- S = K * Q  (S[kv][q]), 4 kv-subtiles of 32 ----
        f32x16 sa[4] = {};
        __builtin_amdgcn_s_setprio(1);
        #pragma unroll
        for (int ks = 0; ks < 8; ++ks){
            const int c8 = (ks<<1) + hi;
            #pragma unroll
            for (int s = 0; s < 4; ++s){
                const int row = (s<<5) + lq;
                bf16x8 kf = *reinterpret_cast<const bf16x8*>(&Kbuf[(row<<7) + ((c8 ^ (row&7))<<3)]);
                sa[s] = __builtin_amdgcn_mfma_f32_32x32x16_bf16(kf, qf[ks], sa[s], 0, 0, 0);
            }
        }
        __builtin_amdgcn_s_setprio(0);

        // ---- online softmax (exp2 domain), per-lane column q ----
        float tmax = sa[0][0];
        #pragma unroll
        for (int s = 0; s < 4; ++s)
            #pragma unroll
            for (int r = 0; r < 16; ++r) tmax = fmaxf(tmax, sa[s][r]);
        tmax = fmaxf(tmax, __shfl_xor(tmax, 32));

        // defer-max (T13): skip rescale when max growth small (P bounded by 2^8)
        const bool defer = __all(tmax <= m_run + 8.0f);
        if (!defer){
            const float mnew = fmaxf(m_run, tmax);
            const float al = __builtin_amdgcn_exp2f(m_run - mnew);
            m_run = mnew;
            l_run *= al;
            #pragma unroll
            for (int dt = 0; dt < 4; ++dt) oacc[dt] *= al;
        }
        float tsum = 0.f;
        #pragma unroll
        for (int s = 0; s < 4; ++s)
            #pragma unroll
            for (int r = 0; r < 16; ++r){
                float p = __builtin_amdgcn_exp2f(sa[s][r] - m_run); sa[s][r] = p; tsum += p;
            }
        tsum += __shfl_xor(tsum, 32);
        l_run += tsum;

        // ---- P -> B-fragments via pack + permlane32_swap (T12); pf[2s],pf[2s+1] from sa[s] ----
        bf16x8 pf[8];
        #define MAKEPF(dA, dB, SV) do { \
            unsigned int a0 = pkbf(SV[0],SV[1]),  b0 = pkbf(SV[2],SV[3]); \
            unsigned int c0 = pkbf(SV[4],SV[5]),  d0 = pkbf(SV[6],SV[7]); \
            unsigned int a1 = pkbf(SV[8],SV[9]),  b1 = pkbf(SV[10],SV[11]); \
            unsigned int c1 = pkbf(SV[12],SV[13]),d1 = pkbf(SV[14],SV[15]); \
            asm("v_permlane32_swap_b32 %0, %1" : "+v"(a0), "+v"(c0)); \
            asm("v_permlane32_swap_b32 %0, %1" : "+v"(b0), "+v"(d0)); \
            asm("v_permlane32_swap_b32 %0, %1" : "+v"(a1), "+v"(c1)); \
            asm("v_permlane32_swap_b32 %0, %1" : "+v"(b1), "+v"(d1)); \
            U8 u; \
            u.w[0] = a0; u.w[1] = b0; u.w[2] = c0; u.w[3] = d0; dA = u.v; \
            u.w[0] = a1; u.w[1] = b1; u.w[2] = c1; u.w[3] = d1; dB = u.v; \
        } while(0)
        #pragma unroll
        for (int s = 0; s < 4; ++s)
            MAKEPF(pf[2*s], pf[2*s+1], sa[s]);
        #undef MAKEPF

        // ---- O^T += V^T * P  (8 kv-subtiles of 16) ----
        __builtin_amdgcn_s_setprio(1);
        #pragma unroll
        for (int dt = 0; dt < 4; ++dt){
            const int rowv = (dt<<5) + lq;
            #pragma unroll
            for (int f = 0; f < 8; ++f){
                const int c8 = (f<<1) + hi;
                bf16x8 vf = *reinterpret_cast<const bf16x8*>(&Vbuf[(rowv<<7) + ((c8 ^ (rowv&7))<<3)]);
                oacc[dt] = __builtin_amdgcn_mfma_f32_32x32x16_bf16(vf, pf[f], oacc[dt], 0, 0, 0);
            }
        }
        __builtin_amdgcn_s_setprio(0);

        __syncthreads();
        buf ^= 1;
    }
    #undef STAGE

    // ---- epilogue: two-phase O^T -> LDS transpose (4 waves per phase) -> global ----
    const float rl = 1.0f / l_run;
    #pragma unroll
    for (int ph = 0; ph < 2; ++ph){
        if ((wave >> 2) == ph){
            unsigned short* oL = smem + (wave & 3)*(32*132);
            #pragma unroll
            for (int dt = 0; dt < 4; ++dt)
                #pragma unroll
                for (int g = 0; g < 4; ++g){
                    u16x4 w = { f2b(oacc[dt][g*4+0]*rl), f2b(oacc[dt][g*4+1]*rl),
                                f2b(oacc[dt][g*4+2]*rl), f2b(oacc[dt][g*4+3]*rl) };
                    *reinterpret_cast<u16x4*>(&oL[lq*132 + (dt<<5) + (hi<<2) + (g<<3)]) = w;
                }
        }
        __syncthreads();
        if ((wave >> 2) == ph){
            const unsigned short* oL = smem + (wave & 3)*(32*132);
            #pragma unroll
            for (int i = 0; i < 16; ++i){
                const int q = (i<<1) + hi;
                u16x4 w = *reinterpret_cast<const u16x4*>(&oL[q*132 + (lq<<2)]);
                *reinterpret_cast<u16x4*>(&aout[(size_t)(b*SEQ + q0w + q)*DIMS + h*HD + (lq<<2)]) = w;
            }
        }
        __syncthreads();
    }
}

// ---------------- launcher ----------------

extern "C" void kernel_launch(void* const* d_in, const int* in_sizes, int n_in,
                              void* d_out, int out_size, void* d_ws, size_t ws_size,
                              hipStream_t stream)
{
    const float* x    = (const float*)d_in[0];
    const float* rope = (const float*)d_in[1];
    const float* wq   = (const float*)d_in[2];
    const float* wk   = (const float*)d_in[3];
    const float* wv   = (const float*)d_in[4];
    const float* wo   = (const float*)d_in[5];
    const float* bo   = (const float*)d_in[6];
    float* out = (float*)d_out;

    char* ws = (char*)d_ws;
    unsigned short* x_bf   = (unsigned short*)(ws + 0);            // 16.8 MB
    unsigned short* wqkv   = (unsigned short*)(ws + 16777216);     // 25.2 MB
    unsigned short* wo_bf  = (unsigned short*)(ws + 41943040);     // 8.4 MB
    float*          cos_t  = (float*)(ws + 50331648);              // 1 MB
    float*          sin_t  = (float*)(ws + 51380224);              // 1 MB
    unsigned short* qkv    = (unsigned short*)(ws + 52428800);     // 50.3 MB
    unsigned short* vt     = (unsigned short*)(ws + 16777216);     // alias wqkv (dead after QKV GEMM)
    unsigned short* a_out  = (unsigned short*)(ws + 0);            // alias x_bf (dead after QKV GEMM)

    // 1. fused prep: x->bf16, 4 weights->bf16, cos/sin
    k_prep<<<dim3(4096, 7), 256, 0, stream>>>(x, wq, wk, wv, wo, rope,
                                              x_bf, wqkv, wqkv + 4194304, wqkv + 8388608, wo_bf,
                                              cos_t, sin_t);

    // 2. QKV projection: 128^2 tile, 32x32x16 MFMA, grid 32*48 = 1536
    k_gemm_bt<0><<<(MROWS/128)*(QKVN/128), 256, 0, stream>>>(x_bf, wqkv, qkv, nullptr, MROWS, QKVN, DIMS);

    // 3. fused K-rope (in place) + V transpose
    k_kropevt<<<4096, 256, 0, stream>>>(qkv, cos_t, sin_t, vt);

    // 4. attention (Q-rope in-register): QBLK=256, KVBLK=128, 256 blocks = 1/CU, 8 waves
    k_attn<<<dim3(SEQ/256, BATCH*HEADS), 512, 0, stream>>>(qkv, vt, cos_t, sin_t, a_out);

    // 5. output projection + bias
    k_gemm_bt<1><<<(MROWS/128)*(DIMS/128), 256, 0, stream>>>(a_out, wo_bf, out, bo, MROWS, DIMS, DIMS);
}

// Round 15
// 271.002 us; speedup vs baseline: 1.0706x; 1.0098x over previous
//
#include <hip/hip_runtime.h>
#include <hip/hip_bf16.h>
#include <stdint.h>

// Problem constants
#define DIMS  2048
#define HEADS 16
#define HD    128
#define BATCH 2
#define SEQ   2048
#define MROWS (BATCH*SEQ)   // 4096
#define QKVN  (3*DIMS)      // 6144

using bf16x8 = __attribute__((ext_vector_type(8))) short;
using f32x4  = __attribute__((ext_vector_type(4))) float;
using f32x16 = __attribute__((ext_vector_type(16))) float;
using u16x4  = __attribute__((ext_vector_type(4))) unsigned short;

__device__ __forceinline__ unsigned short f2b(float f){
    __hip_bfloat16 h = __float2bfloat16(f);
    return *reinterpret_cast<unsigned short*>(&h);
}
__device__ __forceinline__ float b2f(unsigned short u){
    __hip_bfloat16 h;
    *reinterpret_cast<unsigned short*>(&h) = u;
    return __bfloat162float(h);
}
__device__ __forceinline__ unsigned int pkbf(float lo, float hi){
    return (unsigned int)f2b(lo) | ((unsigned int)f2b(hi) << 16);
}

// async global->LDS, 16B per lane. LDS dest is wave-uniform base (+lane*16 implicit).
__device__ __forceinline__ void glds16(const void* g, void* l){
    __builtin_amdgcn_global_load_lds(
        (const __attribute__((address_space(1))) unsigned int*)g,
        (__attribute__((address_space(3))) unsigned int*)l, 16, 0, 0);
}

// ---------------- fused prep: x->bf16, 4x w->bf16, cos/sin table ----------------
// grid (4096, 7): y 0..3 -> weight y; y 4..5 -> x halves; y 6 -> cossin (1024 blocks active)

__global__ void k_prep(const float* __restrict__ x,
                       const float* __restrict__ w0, const float* __restrict__ w1,
                       const float* __restrict__ w2, const float* __restrict__ w3,
                       const float* __restrict__ rope,
                       unsigned short* __restrict__ x_bf,
                       unsigned short* __restrict__ d0, unsigned short* __restrict__ d1,
                       unsigned short* __restrict__ d2, unsigned short* __restrict__ d3,
                       float* __restrict__ ct, float* __restrict__ st){
    const int y = blockIdx.y;
    if (y == 6){
        const int i = blockIdx.x*blockDim.x + threadIdx.x;
        if (i >= SEQ*HD) return;
        const float v = rope[i];
        ct[i] = cosf(v);
        st[i] = sinf(v);
        return;
    }
    const float* src;
    unsigned short* dst;
    size_t off = 0;
    if      (y == 0){ src = w0; dst = d0; }
    else if (y == 1){ src = w1; dst = d1; }
    else if (y == 2){ src = w2; dst = d2; }
    else if (y == 3){ src = w3; dst = d3; }
    else            { src = x;  dst = x_bf; off = (size_t)(y - 4) * 1048576; }
    const size_t i = off + blockIdx.x*blockDim.x + threadIdx.x;
    const float4 v = reinterpret_cast<const float4*>(src)[i];
    u16x4 o = { f2b(v.x), f2b(v.y), f2b(v.z), f2b(v.w) };
    *reinterpret_cast<u16x4*>(dst + 4*i) = o;
}

// ---------------- fused K-rope + V-transpose ----------------
// grid 4096 x 256. bid < 2048: RoPE in-place on K section (bf16x8 vectorized).
// bid >= 2048: V transpose qkv[b][l][2*DIMS + h*128+d] -> vt[(b*16+h)*128+d][l].
// NOTE (R9/R10 lesson): fusing these into the GEMM epilogue regressed twice —
// LDS +1KB cost a blocks/CU step (R9), multi-region epilogue cost +32 VGPR (R10).
// The GEMM plateau depends on its lean 76-VGPR / 32KB-LDS body; keep this separate.

__global__ void k_kropevt(unsigned short* __restrict__ qkv,
                          const float* __restrict__ ct, const float* __restrict__ st,
                          unsigned short* __restrict__ vt){
    __shared__ unsigned short t[64*68];
    const int bid = blockIdx.x;
    if (bid < 2048){
        const int idx = bid*blockDim.x + threadIdx.x;   // 524288
        const int d0 = (idx & 7) << 3;
        const int h  = (idx >> 3) & (HEADS-1);
        const int l  = (idx >> 7) & (SEQ-1);
        const int b  = idx >> 18;
        const float4* cp = reinterpret_cast<const float4*>(ct + l*HD + d0);
        const float4* sp = reinterpret_cast<const float4*>(st + l*HD + d0);
        const float4 cl0 = cp[0],  cl1 = cp[1];
        const float4 sl0 = sp[0],  sl1 = sp[1];
        const float4 cu0 = cp[16], cu1 = cp[17];
        const float4 su0 = sp[16], su1 = sp[17];
        const float cl[8] = {cl0.x,cl0.y,cl0.z,cl0.w, cl1.x,cl1.y,cl1.z,cl1.w};
        const float sl[8] = {sl0.x,sl0.y,sl0.z,sl0.w, sl1.x,sl1.y,sl1.z,sl1.w};
        const float cu[8] = {cu0.x,cu0.y,cu0.z,cu0.w, cu1.x,cu1.y,cu1.z,cu1.w};
        const float su[8] = {su0.x,su0.y,su0.z,su0.w, su1.x,su1.y,su1.z,su1.w};
        unsigned short* rp = qkv + (size_t)(b*SEQ + l)*QKVN + DIMS + h*HD + d0;  // K section
        bf16x8 lo = *reinterpret_cast<const bf16x8*>(rp);
        bf16x8 hi = *reinterpret_cast<const bf16x8*>(rp + 64);
        bf16x8 olo, ohi;
        #pragma unroll
        for (int j = 0; j < 8; ++j){
            const float x1 = b2f((unsigned short)lo[j]);
            const float x2 = b2f((unsigned short)hi[j]);
            olo[j] = (short)f2b(x1*cl[j] - x2*sl[j]);
            ohi[j] = (short)f2b(x2*cu[j] + x1*su[j]);
        }
        *reinterpret_cast<bf16x8*>(rp)      = olo;
        *reinterpret_cast<bf16x8*>(rp + 64) = ohi;
        return;
    }
    // ---- V transpose ----
    const int bid2 = bid - 2048;
    const int lt = bid2 & 31;
    const int dt = (bid2 >> 5) & 1;
    const int bh = bid2 >> 6;
    const int b = bh >> 4, h = bh & 15;
    const int tid = threadIdx.x;
    const int l0 = lt << 6;
    #pragma unroll
    for (int it = 0; it < 4; ++it){
        const int c = tid + (it<<8);
        const int l = c >> 4;
        const int d4 = (c & 15) << 2;
        const u16x4 v = *reinterpret_cast<const u16x4*>(
            qkv + (size_t)(b*SEQ + l0 + l)*QKVN + 2*DIMS + h*HD + (dt<<6) + d4);
        *reinterpret_cast<u16x4*>(&t[l*68 + d4]) = v;
    }
    __syncthreads();
    #pragma unroll
    for (int it = 0; it < 4; ++it){
        const int c = tid + (it<<8);
        const int d = c >> 4;
        const int l4 = (c & 15) << 2;
        u16x4 o = { t[(l4+0)*68 + d], t[(l4+1)*68 + d], t[(l4+2)*68 + d], t[(l4+3)*68 + d] };
        *reinterpret_cast<u16x4*>(&vt[((size_t)bh*HD + (dt<<6) + d)*SEQ + l0 + l4]) = o;
    }
}

// ---------------- 128x128 GEMM (m97 staging) with 32x32x16 MFMA ----------------
// R12 winner: mfma_f32_32x32x16_bf16 (half the MFMA instruction count; VALUBusy 47->16).
// Known artifact: ~12.6M LDS bank conflicts from the 32-row fragment-read shape —
// net still faster than the 16x16 shape. Do not touch.

template<int FINAL>
__global__ __launch_bounds__(256) void k_gemm_bt(
    const unsigned short* __restrict__ A, const unsigned short* __restrict__ B,
    void* __restrict__ C, const float* __restrict__ bias, int M, int N, int K)
{
    __shared__ unsigned short lA[128*64];
    __shared__ unsigned short lB[128*64];
    const int tid  = threadIdx.x;
    const int lane = tid & 63;
    const int wave = tid >> 6;
    const int lq   = lane & 31;
    const int hi   = lane >> 5;

    const int nbx = N >> 7;
    const int nwg = gridDim.x;
    const int cpx = nwg >> 3;
    const int bid = blockIdx.x;
    const int wg  = (bid & 7)*cpx + (bid >> 3);
    const int m0 = (wg / nbx) << 7;
    const int n0 = (wg % nbx) << 7;

    const int wr = (wave >> 1) << 6;
    const int wc = (wave & 1) << 6;

    f32x16 acc[2][2] = {};

    const int srow_base = (wave<<3) + (lane>>3);
    const int schunk = lane & 7;

    for (int k0 = 0; k0 < K; k0 += 64){
        #pragma unroll
        for (int i = 0; i < 4; ++i){
            const int row  = (i<<5) + srow_base;
            const int scol = k0 + ((schunk ^ (row & 7)) << 3);
            glds16(A + (size_t)(m0 + row)*K + scol, &lA[((i<<5) + (wave<<3)) << 6]);
            glds16(B + (size_t)(n0 + row)*K + scol, &lB[((i<<5) + (wave<<3)) << 6]);
        }
        __syncthreads();
        #pragma unroll
        for (int ks = 0; ks < 4; ++ks){
            const int c8 = (ks<<1) + hi;
            bf16x8 af[2], bfr[2];
            #pragma unroll
            for (int ti = 0; ti < 2; ++ti){
                const int rowa = wr + (ti<<5) + lq;
                af[ti] = *reinterpret_cast<const bf16x8*>(&lA[(rowa<<6) + ((c8 ^ (rowa&7))<<3)]);
            }
            #pragma unroll
            for (int tj = 0; tj < 2; ++tj){
                const int rowb = wc + (tj<<5) + lq;
                bfr[tj] = *reinterpret_cast<const bf16x8*>(&lB[(rowb<<6) + ((c8 ^ (rowb&7))<<3)]);
            }
            #pragma unroll
            for (int ti = 0; ti < 2; ++ti)
                #pragma unroll
                for (int tj = 0; tj < 2; ++tj)
                    acc[ti][tj] = __builtin_amdgcn_mfma_f32_32x32x16_bf16(af[ti], bfr[tj], acc[ti][tj], 0, 0, 0);
        }
        __syncthreads();
    }

    // epilogue: D layout (32x32): col=lane&31, row=(r&3)+8*(r>>2)+4*(lane>>5)
    #pragma unroll
    for (int ti = 0; ti < 2; ++ti)
        #pragma unroll
        for (int tj = 0; tj < 2; ++tj)
            #pragma unroll
            for (int r = 0; r < 16; ++r){
                const int row = (r&3) + ((r>>2)<<3) + (hi<<2);
                const int gm = m0 + wr + (ti<<5) + row;
                const int gn = n0 + wc + (tj<<5) + lq;
                const float v = acc[ti][tj][r];
                if (FINAL)
                    reinterpret_cast<float*>(C)[(size_t)gm*N + gn] = v + bias[gn];
                else
                    reinterpret_cast<unsigned short*>(C)[(size_t)gm*N + gn] = f2b(v);
            }
}

// ---------------- flash attention, swapped-operand 32x32, 8-wave, KVBLK=128 ----------------
// R15 change: XCD-aware block remap. Grid (8,32), linear id = x + 8y, XCD ~= id%8.
// Old mapping put the 8 q-blocks sharing one (b,h)'s K/V on 8 DIFFERENT XCDs (each L2
// touched all 32 bh = 32MB K/V -> thrash). New mapping: r=id&7, j=id>>3; bh=r+8*(j&3),
// qi=j>>2 -> each XCD serves exactly 4 bh (4MB K/V = its whole L2), K/V enters L2 once.
// Bijective: fixed bh=(r+8m) <- blocks i=r+8*(m+4*qi), qi=0..7. Work unchanged.

union U8 { unsigned int w[4]; bf16x8 v; };

#define VOFF 32768   // V region offset in smem (elems)

__global__ __launch_bounds__(512, 2) void k_attn(
    const unsigned short* __restrict__ qkv, const unsigned short* __restrict__ vt,
    const float* __restrict__ ct, const float* __restrict__ st,
    unsigned short* __restrict__ aout)
{
    __shared__ unsigned short smem[65536];   // 128 KB

    const int tid  = threadIdx.x;
    const int lane = tid & 63;
    const int wave = tid >> 6;               // 0..7
    const int lq   = lane & 31;
    const int hi   = lane >> 5;

    // XCD-aware remap (see header comment)
    const int lid = blockIdx.x + (blockIdx.y << 3);
    const int rxd = lid & 7, j = lid >> 3;
    const int bh  = rxd + ((j & 3) << 3);
    const int qi  = j >> 2;                  // 0..7
    const int b = bh >> 4, h = bh & 15;
    const int q0w = (qi << 8) + (wave << 5);

    const unsigned short* Kb = qkv + (size_t)b*SEQ*QKVN + DIMS + h*HD;
    const unsigned short* Vb = vt + (size_t)bh*HD*SEQ;

    // Q fragments (B-operand: col=q=lane&31, k=hi*8+j) with in-register RoPE,
    // pre-scaled by log2e/sqrt(HD). d(ks,j) = ks*16 + hi*8 + j; pair = qf[ks+4][j].
    bf16x8 qf[8];
    {
        const float qscale = 0.08838834764831845f * 1.4426950408889634f;
        const int l = q0w + lq;
        const unsigned short* qp = qkv + (size_t)(b*SEQ + l)*QKVN + h*HD + (hi<<3);
        #pragma unroll
        for (int ks = 0; ks < 8; ++ks)
            qf[ks] = *reinterpret_cast<const bf16x8*>(qp + (ks<<4));
        #pragma unroll
        for (int ks = 0; ks < 4; ++ks){
            const int d0 = (ks<<4) + (hi<<3);
            const float4 c0 = *reinterpret_cast<const float4*>(ct + l*HD + d0);
            const float4 c1 = *reinterpret_cast<const float4*>(ct + l*HD + d0 + 4);
            const float4 s0 = *reinterpret_cast<const float4*>(st + l*HD + d0);
            const float4 s1 = *reinterpret_cast<const float4*>(st + l*HD + d0 + 4);
            const float4 C0 = *reinterpret_cast<const float4*>(ct + l*HD + d0 + 64);
            const float4 C1 = *reinterpret_cast<const float4*>(ct + l*HD + d0 + 68);
            const float4 S0 = *reinterpret_cast<const float4*>(st + l*HD + d0 + 64);
            const float4 S1 = *reinterpret_cast<const float4*>(st + l*HD + d0 + 68);
            const float cl[8] = {c0.x,c0.y,c0.z,c0.w, c1.x,c1.y,c1.z,c1.w};
            const float sl[8] = {s0.x,s0.y,s0.z,s0.w, s1.x,s1.y,s1.z,s1.w};
            const float cu[8] = {C0.x,C0.y,C0.z,C0.w, C1.x,C1.y,C1.z,C1.w};
            const float su[8] = {S0.x,S0.y,S0.z,S0.w, S1.x,S1.y,S1.z,S1.w};
            #pragma unroll
            for (int jj = 0; jj < 8; ++jj){
                const float x1 = b2f((unsigned short)qf[ks][jj]);
                const float x2 = b2f((unsigned short)qf[ks+4][jj]);
                qf[ks][jj]   = (short)f2b((x1*cl[jj] - x2*sl[jj]) * qscale);
                qf[ks+4][jj] = (short)f2b((x2*cu[jj] + x1*su[jj]) * qscale);
            }
        }
    }

    float m_run = -3e38f, l_run = 0.f;
    f32x16 oacc[4] = {};

    // staging: per wave 4 K-calls (4 kv-rows each) + 4 V-calls (4 d-rows each); pitch 128.
    #define STAGE(pb, kv0) do { \
        _Pragma("unroll") \
        for (int i = 0; i < 4; ++i){ \
            const int kr = (wave<<4) + (i<<2) + (lane>>4); \
            glds16(Kb + (size_t)((kv0) + kr)*QKVN + ((((lane&15) ^ (kr&7)))<<3), \
                   &smem[((pb)<<14) + (((wave<<4) + (i<<2))<<7)]); \
            const int dr = (wave<<4) + (i<<2) + (lane>>4); \
            glds16(Vb + (size_t)dr*SEQ + (kv0) + ((((lane&15) ^ (dr&7)))<<3), \
                   &smem[VOFF + ((pb)<<14) + (((wave<<4) + (i<<2))<<7)]); \
        } \
    } while(0)

    int buf = 0;
    STAGE(0, 0);
    __syncthreads();

    for (int t = 0; t < SEQ/128; ++t){
        if (t < SEQ/128 - 1) STAGE(buf^1, (t+1)*128);

        const unsigned short* Kbuf = &smem[buf<<14];
        const unsigned short* Vbuf = &smem[VOFF + (buf<<14)];

        // ---- S = K * Q  (S[kv][q]), 4 kv-subtiles of 32 ----
        f32x16 sa[4] = {};
        __builtin_amdgcn_s_setprio(1);
        #pragma unroll
        for (int ks = 0; ks < 8; ++ks){
            const int c8 = (ks<<1) + hi;
            #pragma unroll
            for (int s = 0; s < 4; ++s){
                const int row = (s<<5) + lq;
                bf16x8 kf = *reinterpret_cast<const bf16x8*>(&Kbuf[(row<<7) + ((c8 ^ (row&7))<<3)]);
                sa[s] = __builtin_amdgcn_mfma_f32_32x32x16_bf16(kf, qf[ks], sa[s], 0, 0, 0);
            }
        }
        __builtin_amdgcn_s_setprio(0);

        // ---- online softmax (exp2 domain), per-lane column q ----
        float tmax = sa[0][0];
        #pragma unroll
        for (int s = 0; s < 4; ++s)
            #pragma unroll
            for (int r = 0; r < 16; ++r) tmax = fmaxf(tmax, sa[s][r]);
        tmax = fmaxf(tmax, __shfl_xor(tmax, 32));

        // defer-max (T13): skip rescale when max growth small (P bounded by 2^8)
        const bool defer = __all(tmax <= m_run + 8.0f);
        if (!defer){
            const float mnew = fmaxf(m_run, tmax);
            const float al = __builtin_amdgcn_exp2f(m_run - mnew);
            m_run = mnew;
            l_run *= al;
            #pragma unroll
            for (int dt = 0; dt < 4; ++dt) oacc[dt] *= al;
        }
        float tsum = 0.f;
        #pragma unroll
        for (int s = 0; s < 4; ++s)
            #pragma unroll
            for (int r = 0; r < 16; ++r){
                float p = __builtin_amdgcn_exp2f(sa[s][r] - m_run); sa[s][r] = p; tsum += p;
            }
        tsum += __shfl_xor(tsum, 32);
        l_run += tsum;

        // ---- P -> B-fragments via pack + permlane32_swap (T12); pf[2s],pf[2s+1] from sa[s] ----
        bf16x8 pf[8];
        #define MAKEPF(dA, dB, SV) do { \
            unsigned int a0 = pkbf(SV[0],SV[1]),  b0 = pkbf(SV[2],SV[3]); \
            unsigned int c0 = pkbf(SV[4],SV[5]),  d0 = pkbf(SV[6],SV[7]); \
            unsigned int a1 = pkbf(SV[8],SV[9]),  b1 = pkbf(SV[10],SV[11]); \
            unsigned int c1 = pkbf(SV[12],SV[13]),d1 = pkbf(SV[14],SV[15]); \
            asm("v_permlane32_swap_b32 %0, %1" : "+v"(a0), "+v"(c0)); \
            asm("v_permlane32_swap_b32 %0, %1" : "+v"(b0), "+v"(d0)); \
            asm("v_permlane32_swap_b32 %0, %1" : "+v"(a1), "+v"(c1)); \
            asm("v_permlane32_swap_b32 %0, %1" : "+v"(b1), "+v"(d1)); \
            U8 u; \
            u.w[0] = a0; u.w[1] = b0; u.w[2] = c0; u.w[3] = d0; dA = u.v; \
            u.w[0] = a1; u.w[1] = b1; u.w[2] = c1; u.w[3] = d1; dB = u.v; \
        } while(0)
        #pragma unroll
        for (int s = 0; s < 4; ++s)
            MAKEPF(pf[2*s], pf[2*s+1], sa[s]);
        #undef MAKEPF

        // ---- O^T += V^T * P  (8 kv-subtiles of 16) ----
        __builtin_amdgcn_s_setprio(1);
        #pragma unroll
        for (int dt = 0; dt < 4; ++dt){
            const int rowv = (dt<<5) + lq;
            #pragma unroll
            for (int f = 0; f < 8; ++f){
                const int c8 = (f<<1) + hi;
                bf16x8 vf = *reinterpret_cast<const bf16x8*>(&Vbuf[(rowv<<7) + ((c8 ^ (rowv&7))<<3)]);
                oacc[dt] = __builtin_amdgcn_mfma_f32_32x32x16_bf16(vf, pf[f], oacc[dt], 0, 0, 0);
            }
        }
        __builtin_amdgcn_s_setprio(0);

        __syncthreads();
        buf ^= 1;
    }
    #undef STAGE

    // ---- epilogue: two-phase O^T -> LDS transpose (4 waves per phase) -> global ----
    const float rl = 1.0f / l_run;
    #pragma unroll
    for (int ph = 0; ph < 2; ++ph){
        if ((wave >> 2) == ph){
            unsigned short* oL = smem + (wave & 3)*(32*132);
            #pragma unroll
            for (int dt = 0; dt < 4; ++dt)
                #pragma unroll
                for (int g = 0; g < 4; ++g){
                    u16x4 w = { f2b(oacc[dt][g*4+0]*rl), f2b(oacc[dt][g*4+1]*rl),
                                f2b(oacc[dt][g*4+2]*rl), f2b(oacc[dt][g*4+3]*rl) };
                    *reinterpret_cast<u16x4*>(&oL[lq*132 + (dt<<5) + (hi<<2) + (g<<3)]) = w;
                }
        }
        __syncthreads();
        if ((wave >> 2) == ph){
            const unsigned short* oL = smem + (wave & 3)*(32*132);
            #pragma unroll
            for (int i = 0; i < 16; ++i){
                const int q = (i<<1) + hi;
                u16x4 w = *reinterpret_cast<const u16x4*>(&oL[q*132 + (lq<<2)]);
                *reinterpret_cast<u16x4*>(&aout[(size_t)(b*SEQ + q0w + q)*DIMS + h*HD + (lq<<2)]) = w;
            }
        }
        __syncthreads();
    }
}

// ---------------- launcher ----------------

extern "C" void kernel_launch(void* const* d_in, const int* in_sizes, int n_in,
                              void* d_out, int out_size, void* d_ws, size_t ws_size,
                              hipStream_t stream)
{
    const float* x    = (const float*)d_in[0];
    const float* rope = (const float*)d_in[1];
    const float* wq   = (const float*)d_in[2];
    const float* wk   = (const float*)d_in[3];
    const float* wv   = (const float*)d_in[4];
    const float* wo   = (const float*)d_in[5];
    const float* bo   = (const float*)d_in[6];
    float* out = (float*)d_out;

    char* ws = (char*)d_ws;
    unsigned short* x_bf   = (unsigned short*)(ws + 0);            // 16.8 MB
    unsigned short* wqkv   = (unsigned short*)(ws + 16777216);     // 25.2 MB
    unsigned short* wo_bf  = (unsigned short*)(ws + 41943040);     // 8.4 MB
    float*          cos_t  = (float*)(ws + 50331648);              // 1 MB
    float*          sin_t  = (float*)(ws + 51380224);              // 1 MB
    unsigned short* qkv    = (unsigned short*)(ws + 52428800);     // 50.3 MB
    unsigned short* vt     = (unsigned short*)(ws + 16777216);     // alias wqkv (dead after QKV GEMM)
    unsigned short* a_out  = (unsigned short*)(ws + 0);            // alias x_bf (dead after QKV GEMM)

    // 1. fused prep: x->bf16, 4 weights->bf16, cos/sin
    k_prep<<<dim3(4096, 7), 256, 0, stream>>>(x, wq, wk, wv, wo, rope,
                                              x_bf, wqkv, wqkv + 4194304, wqkv + 8388608, wo_bf,
                                              cos_t, sin_t);

    // 2. QKV projection: 128^2 tile, 32x32x16 MFMA, grid 32*48 = 1536
    k_gemm_bt<0><<<(MROWS/128)*(QKVN/128), 256, 0, stream>>>(x_bf, wqkv, qkv, nullptr, MROWS, QKVN, DIMS);

    // 3. fused K-rope (in place) + V transpose
    k_kropevt<<<4096, 256, 0, stream>>>(qkv, cos_t, sin_t, vt);

    // 4. attention (Q-rope in-register, XCD-local bh mapping): 256 blocks = 1/CU, 8 waves
    k_attn<<<dim3(SEQ/256, BATCH*HEADS), 512, 0, stream>>>(qkv, vt, cos_t, sin_t, a_out);

    // 5. output projection + bias
    k_gemm_bt<1><<<(MROWS/128)*(DIMS/128), 256, 0, stream>>>(a_out, wo_bf, out, bo, MROWS, DIMS, DIMS);
}